// Round 16
// baseline (5394.617 us; speedup 1.0000x reference)
//
#include <hip/hip_runtime.h>
#include <cstdint>
#include <cstddef>

// ---------------------------------------------------------------------------
// TaggingFNNDecoder round 23.
// r22 ~neutral. Model recalibration: step 18.5us with ~3us compute => each
// system-scope LLC RT costs ~1.5-2us; critical cycle has ~10 RT events. The
// lever is RT COUNT. Also r8/r9 re-read: all-poll barrier was EXONERATED
// (r9's master barrier kept the 5GB WRITE -> spills, not polling).
// Two RT removals:
//  (1) P1 deferred wait -> single-level all-poll (tid<128 poll 128 slots,
//      s_sleep-throttled) replacing master+bcast (2 RTs -> 1).
//  (2) packed e-slots: head writes per-batch 32 x 32B slots {cnt,S,e[4]}
//      (e stores, drain, then {cnt,S}). Worker lanes poll their OWN two
//      slots with the dwordx4s that carry their e-quads -> on success the
//      operands+S are already in registers. Eliminates the separate sm RT,
//      the post-poll syncthreads, and the sSl broadcast. Same-line ordering
//      (e drained before cnt) makes cnt => e-valid.
// Falsifiers: VGPR 256 => trap (revert); FETCH/WRITE explosion or dur
// regression => poll storm (revert piece 2); hang => ordering bug.
// ---------------------------------------------------------------------------

#define Bz   32
#define Tz   256
#define Dz   1024
#define Hz   512
#define NK   128
#define IN0  1152
#define NBLK 256
#define BH   16384      // Bz*Hz

typedef float vf4 __attribute__((ext_vector_type(4)));
typedef unsigned long long ull;

__device__ __forceinline__ void ldsc4(vf4& d, const float* p) {
  asm volatile("global_load_dwordx4 %0, %1, off sc0 sc1" : "=v"(d) : "v"(p));
}
__device__ __forceinline__ void ldg1(float& d, const float* p) {
  asm volatile("global_load_dword %0, %1, off" : "=v"(d) : "v"(p));
}
__device__ __forceinline__ void stsc1(float* p, float v) {
  asm volatile("global_store_dword %0, %1, off sc0 sc1" :: "v"(p), "v"(v) : "memory");
}
__device__ __forceinline__ void stsc2u(ull* p, ull v) {
  asm volatile("global_store_dwordx2 %0, %1, off sc0 sc1" :: "v"(p), "v"(v) : "memory");
}
#define FENCE8(c, a0,a1,a2,a3,a4,a5,a6,a7) \
  asm volatile("s_waitcnt vmcnt(" #c ")" : "+v"(a0),"+v"(a1),"+v"(a2),"+v"(a3), \
               "+v"(a4),"+v"(a5),"+v"(a6),"+v"(a7) :: "memory")

// NOTE: macro params must not collide with vector member names x/y/z/w.
#define FMA4(acc, W_, A_) \
  acc = fmaf((W_).x,(A_).x, fmaf((W_).y,(A_).y, fmaf((W_).z,(A_).z, fmaf((W_).w,(A_).w,(acc)))))

__device__ __forceinline__ float sigf(float x) { return 1.0f / (1.0f + expf(-x)); }

// ---------------- full barrier (prologue only) -----------------------------
__device__ __forceinline__ void gbar(unsigned int* slots, unsigned int* bcast,
                                     int gidx, bool master, unsigned int g) {
  asm volatile("s_waitcnt vmcnt(0)" ::: "memory");
  __syncthreads();
  if (threadIdx.x == 0)
    __hip_atomic_store(slots + gidx * 16, g,
                       __ATOMIC_RELAXED, __HIP_MEMORY_SCOPE_SYSTEM);
  if (master) {
    if (threadIdx.x < 128) {
      unsigned int* wsl = slots + threadIdx.x * 16;
      while (__hip_atomic_load(wsl, __ATOMIC_RELAXED, __HIP_MEMORY_SCOPE_SYSTEM) < g)
        __builtin_amdgcn_s_sleep(1);
    }
    __syncthreads();
    if (threadIdx.x == 0) {
      asm volatile("s_waitcnt vmcnt(0)" ::: "memory");
      __hip_atomic_store(bcast, g, __ATOMIC_RELAXED, __HIP_MEMORY_SCOPE_SYSTEM);
    }
  } else if (threadIdx.x == 0) {
    while (__hip_atomic_load(bcast, __ATOMIC_RELAXED, __HIP_MEMORY_SCOPE_SYSTEM) < g)
      __builtin_amdgcn_s_sleep(1);
  }
  __syncthreads();
}

// ---------------- arrive-only: drain (stores+loads), publish slot ----------
__device__ __forceinline__ void garrive(unsigned int* slots, int gidx,
                                        unsigned int g) {
  asm volatile("s_waitcnt vmcnt(0)" ::: "memory");
  __syncthreads();
  if (threadIdx.x == 0)
    __hip_atomic_store(slots + gidx * 16, g,
                       __ATOMIC_RELAXED, __HIP_MEMORY_SCOPE_SYSTEM);
}

// 16-row FMA over all rows r for one act vf4 from LDS base BASE at col KOFF.
#define FMAROW(r, AV, BASE, KOFF) \
  { vf4 wv = *(const vf4*)&BASE[r][KOFF]; FMA4(A##r, wv, AV); }
#define R16A(OP, AV, BASE, KOFF) \
  OP(0,AV,BASE,KOFF) OP(1,AV,BASE,KOFF) OP(2,AV,BASE,KOFF) OP(3,AV,BASE,KOFF) \
  OP(4,AV,BASE,KOFF) OP(5,AV,BASE,KOFF) OP(6,AV,BASE,KOFF) OP(7,AV,BASE,KOFF) \
  OP(8,AV,BASE,KOFF) OP(9,AV,BASE,KOFF) OP(10,AV,BASE,KOFF) OP(11,AV,BASE,KOFF) \
  OP(12,AV,BASE,KOFF) OP(13,AV,BASE,KOFF) OP(14,AV,BASE,KOFF) OP(15,AV,BASE,KOFF)

// 4-stage value-halving butterfly over 16-lane ks groups; after it, lane ks's
// A0 holds the full k-sum of row rev4(ks). (r6-validated scheme.)
#define RED16 { \
  { const bool hi = (ks & 1) != 0; \
    float s0=hi?A0:A8, s1=hi?A1:A9, s2=hi?A2:A10, s3=hi?A3:A11; \
    float s4=hi?A4:A12, s5=hi?A5:A13, s6=hi?A6:A14, s7=hi?A7:A15; \
    float k0=hi?A8:A0, k1=hi?A9:A1, k2=hi?A10:A2, k3=hi?A11:A3; \
    float k4=hi?A12:A4, k5=hi?A13:A5, k6=hi?A14:A6, k7=hi?A15:A7; \
    A0=k0+__shfl_xor(s0,1,64); A1=k1+__shfl_xor(s1,1,64); \
    A2=k2+__shfl_xor(s2,1,64); A3=k3+__shfl_xor(s3,1,64); \
    A4=k4+__shfl_xor(s4,1,64); A5=k5+__shfl_xor(s5,1,64); \
    A6=k6+__shfl_xor(s6,1,64); A7=k7+__shfl_xor(s7,1,64); } \
  { const bool hi = (ks & 2) != 0; \
    float s0=hi?A0:A4, s1=hi?A1:A5, s2=hi?A2:A6, s3=hi?A3:A7; \
    float k0=hi?A4:A0, k1=hi?A5:A1, k2=hi?A6:A2, k3=hi?A7:A3; \
    A0=k0+__shfl_xor(s0,2,64); A1=k1+__shfl_xor(s1,2,64); \
    A2=k2+__shfl_xor(s2,2,64); A3=k3+__shfl_xor(s3,2,64); } \
  { const bool hi = (ks & 4) != 0; \
    float s0=hi?A0:A2, s1=hi?A1:A3; float k0=hi?A2:A0, k1=hi?A3:A1; \
    A0=k0+__shfl_xor(s0,4,64); A1=k1+__shfl_xor(s1,4,64); } \
  { const bool hi = (ks & 8) != 0; \
    float s0=hi?A0:A1; float k0=hi?A1:A0; \
    A0=k0+__shfl_xor(s0,8,64); } }

#define ZERO16 A0=0.f;A1=0.f;A2=0.f;A3=0.f;A4=0.f;A5=0.f;A6=0.f;A7=0.f; \
               A8=0.f;A9=0.f;A10=0.f;A11=0.f;A12=0.f;A13=0.f;A14=0.f;A15=0.f;

// gate nonlinearity + h write. tid<64: cu=tid&3 (unit), cbl=tid>>2 (batch).
#define GATES(CREG, HDST) \
  __syncthreads(); \
  if (tid < 64) { \
    float gi = gbuf[cu][cbl],      gf = gbuf[4 + cu][cbl]; \
    float gg = gbuf[8 + cu][cbl],  go = gbuf[12 + cu][cbl]; \
    CREG = sigf(gf) * CREG + sigf(gi) * tanhf(gg); \
    stsc1(HDST + (size_t)(pg * 16 + cbl) * Hz + jg * 4 + cu, \
          sigf(go) * tanhf(CREG)); \
  }

// ---------------- head critical: GEMV + packed e-slot release --------------
// Pair layout: n=tid>>1, kh=tid&1; shfl_xor(p,1) completes the dot.
// e written into packed slots (batch region eslb = esl + bb*256 floats;
// slot s (32B) = {w0 cnt, w1 S, w2..w5 e[4s..4s+3], w6..w7 pad}); raw logit
// to lgg; after drain, {cnt,S} stored to all 32 slots (release).
__device__ void c_head_crit(const float* src, int bb,
                            const float* __restrict__ W_out,
                            const float* __restrict__ b_out,
                            float* __restrict__ esl, float* __restrict__ lggb,
                            float* wred, unsigned int fval) {
  const int tid = threadIdx.x;
  const int n = tid >> 1, kh = tid & 1;
  float* eslb = esl + (size_t)bb * 256;
  float p = 0.0f;
  const float* w  = W_out + (size_t)n * Hz + kh * 256;
  const float* s2 = src + kh * 256;
  #pragma unroll 8
  for (int k = 0; k < 256; k += 4) {
    vf4 sv = *(const vf4*)(s2 + k);
    vf4 wv = *(const vf4*)(w + k);
    p += sv.x * wv.x + sv.y * wv.y + sv.z * wv.z + sv.w * wv.w;
  }
  p += __shfl_xor(p, 1, 64);            // both lanes of the pair: full dot
  float logit = p + b_out[n];
  float e = expf(logit);
  if (kh == 0) {
    stsc1(lggb + n, logit);             // raw logits for buddy out-softmax
    stsc1(eslb + (n >> 2) * 8 + 2 + (n & 3), e);   // e into its slot word
  }
  // S = sum_n e  (each n appears twice across lanes -> *0.5)
  float s = e;
  #pragma unroll
  for (int off = 32; off >= 1; off >>= 1) s += __shfl_xor(s, off);
  if ((tid & 63) == 0) wred[tid >> 6] = s;
  __syncthreads();
  float S = (wred[0] + wred[1] + wred[2] + wred[3]) * 0.5f;
  asm volatile("s_waitcnt vmcnt(0)" ::: "memory");
  __syncthreads();
  // release: {cnt,S} into w0,w1 of each of the 32 slots (one dwordx2 each)
  if (tid < 32) {
    ull v = ((ull)__float_as_uint(S) << 32) | (ull)fval;   // w0=cnt, w1=S
    stsc2u((ull*)(eslb + tid * 8), v);
  }
}

// ---------------- buddy: masked output softmax from global logits ----------
__device__ void c_head_out(int t, int bb, const float* __restrict__ mask,
                           float* __restrict__ out,
                           const float* __restrict__ lggb, float* wred) {
  const int tid = threadIdx.x;
  const int n = tid & 127;
  float lg = 0.0f;
  if (tid < 128)
    lg = __hip_atomic_load(lggb + n, __ATOMIC_RELAXED, __HIP_MEMORY_SCOPE_SYSTEM);
  float mk = (tid < 128) ? mask[bb * Tz + t] : 1.0f;
  float lm = (tid < 128) ? (lg + (1.0f - mk) * (-1e32f)) : -3.0e38f;
  float m2 = lm;
  #pragma unroll
  for (int off = 32; off >= 1; off >>= 1) m2 = fmaxf(m2, __shfl_xor(m2, off));
  if ((tid & 63) == 0 && tid < 128) wred[4 + (tid >> 6)] = m2;
  __syncthreads();
  float M2 = fmaxf(wred[4], wred[5]);
  float e2 = (tid < 128) ? expf(lm - M2) : 0.0f;
  float s2r = e2;
  #pragma unroll
  for (int off = 32; off >= 1; off >>= 1) s2r += __shfl_xor(s2r, off);
  if ((tid & 63) == 0 && tid < 128) wred[6 + (tid >> 6)] = s2r;
  __syncthreads();
  float S2 = wred[6] + wred[7];
  if (tid < 128) out[((size_t)bb * Tz + t) * NK + n] = e2 / S2;
}

// ---------------- Xpre GEMM (r1's verified kernel, generalized) -----------
// Xpre[n][(t-t0)*32+b] = sum_k hiddens[b][t][k]*W_ih0[n][k] + b_ih0[n]+b_hh0[n]
__global__ void __launch_bounds__(256)
xpre_kernel(const float* __restrict__ hiddens, const float* __restrict__ W_ih0,
            const float* __restrict__ b_ih0, const float* __restrict__ b_hh0,
            float* __restrict__ Xpre, int t0, int colTiles, int cstride) {
  __shared__ float Ws[16][64];
  __shared__ float Hs[16][64];
  const int tid = threadIdx.x;
  const int bx = blockIdx.x % colTiles;
  const int by = blockIdx.x / colTiles;
  const int n0 = by * 64, c0 = bx * 64;
  const int tx = tid & 15, ty = tid >> 4;
  const int ldn = tid >> 2;
  const int ldk = (tid & 3) * 4;

  const int bb = ldn & 31;
  const int tt = t0 + (c0 >> 5) + (ldn >> 5);
  const float* hsrc = hiddens + ((size_t)bb * Tz + tt) * Dz + ldk;
  const float* wsrc = W_ih0 + (size_t)(n0 + ldn) * IN0 + ldk;

  float acc[4][4] = {};
  vf4 wv = *(const vf4*)(wsrc);
  vf4 hv = *(const vf4*)(hsrc);
  for (int k0 = 0; k0 < Dz; k0 += 16) {
    __syncthreads();
    Ws[ldk + 0][ldn] = wv.x; Ws[ldk + 1][ldn] = wv.y;
    Ws[ldk + 2][ldn] = wv.z; Ws[ldk + 3][ldn] = wv.w;
    Hs[ldk + 0][ldn] = hv.x; Hs[ldk + 1][ldn] = hv.y;
    Hs[ldk + 2][ldn] = hv.z; Hs[ldk + 3][ldn] = hv.w;
    __syncthreads();
    if (k0 + 16 < Dz) {
      wv = *(const vf4*)(wsrc + k0 + 16);
      hv = *(const vf4*)(hsrc + k0 + 16);
    }
    #pragma unroll
    for (int k = 0; k < 16; ++k) {
      vf4 a4 = *(const vf4*)&Ws[k][ty * 4];
      vf4 b4 = *(const vf4*)&Hs[k][tx * 4];
      acc[0][0] += a4.x * b4.x; acc[0][1] += a4.x * b4.y; acc[0][2] += a4.x * b4.z; acc[0][3] += a4.x * b4.w;
      acc[1][0] += a4.y * b4.x; acc[1][1] += a4.y * b4.y; acc[1][2] += a4.y * b4.z; acc[1][3] += a4.y * b4.w;
      acc[2][0] += a4.z * b4.x; acc[2][1] += a4.z * b4.y; acc[2][2] += a4.z * b4.z; acc[2][3] += a4.z * b4.w;
      acc[3][0] += a4.w * b4.x; acc[3][1] += a4.w * b4.y; acc[3][2] += a4.w * b4.z; acc[3][3] += a4.w * b4.w;
    }
  }
  #pragma unroll
  for (int i = 0; i < 4; ++i) {
    int n = n0 + ty * 4 + i;
    float bi = b_ih0[n] + b_hh0[n];
    vf4 v; v.x = acc[i][0] + bi; v.y = acc[i][1] + bi;
    v.z = acc[i][2] + bi; v.w = acc[i][3] + bi;
    *(vf4*)(Xpre + (size_t)n * cstride + c0 + tx * 4) = v;
  }
}

// ---------------- the persistent kernel -----------------------------------
__global__ void __launch_bounds__(256)
seq_kernel(const float* __restrict__ hiddens,
           const float* __restrict__ h_t, const float* __restrict__ c_t,
           const float* __restrict__ mask,
           const float* __restrict__ W_out, const float* __restrict__ b_out,
           const float* __restrict__ W_ih0, const float* __restrict__ W_hh0,
           const float* __restrict__ W_ih1, const float* __restrict__ W_hh1,
           const float* __restrict__ b_ih1, const float* __restrict__ b_hh1,
           const float* __restrict__ Xpre, float* __restrict__ out,
           float* __restrict__ h1g, float* __restrict__ h2g,
           float* __restrict__ esl, float* __restrict__ c1g, float* __restrict__ c2g,
           float* __restrict__ lgg,
           unsigned int* bar, int t0, int nsteps, int cstride) {
  __shared__ float wA[16][640];     // [W_hh0(512) | W_ih0 sm-cols(128)]
  __shared__ float wB[16][1024];    // [W_ih1(512) | W_hh1(512)]
  __shared__ float gbuf[16][17];
  __shared__ float biasB[16];
  __shared__ float hsg[512];
  __shared__ float wred[8];

  const int tid = threadIdx.x;
  const int bid = blockIdx.x;
  const int jg  = bid >> 1;          // j-group 0..127 (4 hidden units)
  const int pg  = bid & 1;           // batch-group 0..1 (16 batches)
  const int ks  = tid & 15;          // k-slice 0..15
  const int bbl = tid >> 4;          // local batch 0..15
  const int bbg = pg * 16 + bbl;     // global batch
  const int ks4 = ks * 4;
  const int cu  = tid & 3, cbl = tid >> 2;   // GATES mapping (tid<64)
  const int rr  = ((ks & 1) << 3) | ((ks & 2) << 1) | ((ks & 4) >> 1) | ((ks & 8) >> 3);
  const int rowG = ((rr >> 2) * Hz) + jg * 4 + (rr & 3);   // butterfly-out row
  // head blocks: bid<32; batch remapped into the block's own pg-group.
  const int hb = ((bid & 1) << 4) | (bid >> 1);
  // buddy blocks: bid in [32,64); masked out-softmax for batch bb2 (own pg).
  const bool isbud = (bid >= 32 && bid < 64);
  const int  bb2   = isbud ? (((bid & 1) << 4) | ((bid >> 1) - 16)) : 0;

  // bar layout (uints): [0..2047] g0 slots (64B stride), [2048..4095] g1
  // slots, [4096 + pg*16] bcast words (prologue gbar only).
  unsigned int* barg = bar + pg * 2048;
  unsigned int* bcst = bar + 4096 + pg * 16;
  const int  gidx    = bid >> 1;            // slot index within group
  const bool gmaster = (gidx == 127);       // bid 254 / 255

  // this lane's packed e-slots (batch bbg, quads ks and 16+ks)
  const float* slotA = esl + (size_t)bbg * 256 + (size_t)ks * 8;
  const float* slotB = esl + (size_t)bbg * 256 + (size_t)(16 + ks) * 8;

  // ---- one-time: weights -> LDS (block-private rows, read-only source) ----
  #pragma clang loop unroll(disable)
  for (int r = 0; r < 16; ++r) {
    const int row = ((r >> 2) * Hz) + jg * 4 + (r & 3);
    if (tid * 4 < 512)
      *(vf4*)&wA[r][tid * 4] = *(const vf4*)(W_hh0 + (size_t)row * Hz + tid * 4);
    if (tid * 4 < 128)
      *(vf4*)&wA[r][512 + tid * 4] = *(const vf4*)(W_ih0 + (size_t)row * IN0 + 1024 + tid * 4);
    if (tid * 4 < 512) {
      *(vf4*)&wB[r][tid * 4]       = *(const vf4*)(W_ih1 + (size_t)row * Hz + tid * 4);
      *(vf4*)&wB[r][512 + tid * 4] = *(const vf4*)(W_hh1 + (size_t)row * Hz + tid * 4);
    }
  }
  if (tid < 16) {
    const int row = ((tid >> 2) * Hz) + jg * 4 + (tid & 3);
    biasB[tid] = b_ih1[row] + b_hh1[row];
  }

  // ---- c-state in registers (tid<64: unit cu, batch cbl) ----
  float c1r = 0.0f, c2r = 0.0f;
  if (tid < 64) {
    const size_t ci = (size_t)(pg * 16 + cbl) * Hz + jg * 4 + cu;
    if (t0 == 0) { c1r = c_t[ci]; c2r = c_t[BH + ci]; }
    else         { c1r = c1g[ci]; c2r = c2g[ci]; }
  }

  if (t0 == 0) {
    // stage h_t into parity-1 h buffers; compute e/S(-1)
    if (bid < 32 && tid < 128) {
      vf4 v1 = *(const vf4*)(h_t + (size_t)hb * Hz + tid * 4);
      vf4 v2 = *(const vf4*)(h_t + BH + (size_t)hb * Hz + tid * 4);
      float* d1 = h1g + BH + (size_t)hb * Hz + tid * 4;
      float* d2 = h2g + BH + (size_t)hb * Hz + tid * 4;
      stsc1(d1, v1.x); stsc1(d1 + 1, v1.y); stsc1(d1 + 2, v1.z); stsc1(d1 + 3, v1.w);
      stsc1(d2, v2.x); stsc1(d2 + 1, v2.y); stsc1(d2 + 2, v2.z); stsc1(d2 + 3, v2.w);
    }
    if (bid < 32) {
      if (tid < 128)
        *(vf4*)&hsg[tid * 4] = *(const vf4*)(hiddens + (size_t)hb * Tz * Dz + tid * 4);
      __syncthreads();
      c_head_crit(hsg, hb, W_out, b_out, esl, lgg + hb * NK, wred, 0u);
    }
  }
  __syncthreads();
  unsigned int g = 1;
  gbar(barg, bcst, gidx, gmaster, g); ++g;      // g is now 2

  // ---- loop-carried phase-A operands: ca = h1prev(t) [= prev iter's aa] --
  vf4 ca0,ca1,ca2,ca3,ca4,ca5,ca6,ca7;
  {
    const float* hp = h1g + ((t0 + 1) & 1) * BH + (size_t)bbg * Hz + ks4;
    ldsc4(ca0, hp);        ldsc4(ca1, hp + 64);  ldsc4(ca2, hp + 128);
    ldsc4(ca3, hp + 192);  ldsc4(ca4, hp + 256); ldsc4(ca5, hp + 320);
    ldsc4(ca6, hp + 384);  ldsc4(ca7, hp + 448);
    FENCE8(0, ca0,ca1,ca2,ca3,ca4,ca5,ca6,ca7);
  }

  #pragma clang loop unroll(disable)
  for (int k = 0; k < nsteps; ++k) {
    const int t = t0 + k;
    float*       h1cur  = h1g + (t & 1) * BH;
    const float* h2prev = h2g + ((t + 1) & 1) * BH;
    float*       h2cur  = h2g + (t & 1) * BH;
    float A0,A1,A2,A3,A4,A5,A6,A7,A8,A9,A10,A11,A12,A13,A14,A15;
    vf4 ab0,ab1,ab2,ab3,ab4,ab5,ab6,ab7;   // phase-B h2prev operands

    // ============ Phase A: layer-0 gates (ah = carried ca regs) ===========
    {
      float xv;
      ldg1(xv, Xpre + (size_t)rowG * cstride + k * 32 + bbg);
      ZERO16
      R16A(FMAROW, ca0, wA, ks4 +   0)
      R16A(FMAROW, ca1, wA, ks4 +  64)
      R16A(FMAROW, ca2, wA, ks4 + 128)
      R16A(FMAROW, ca3, wA, ks4 + 192)
      R16A(FMAROW, ca4, wA, ks4 + 256)
      R16A(FMAROW, ca5, wA, ks4 + 320)
      R16A(FMAROW, ca6, wA, ks4 + 384)
      R16A(FMAROW, ca7, wA, ks4 + 448)
      RED16
      const float partA = A0;            // ah contribution, reduced (1 reg)
      // ---- acquire e/S(t-1): per-lane self-poll of packed slots ----------
      // (tiny live set; slot fetch carries cnt,S AND the e-quads)
      vf4 pa0, pa1, pb0, pb1;
      if (k > 0) {
        const unsigned int tgt = (unsigned int)k;
        for (;;) {
          ldsc4(pa0, slotA); ldsc4(pa1, slotA + 4);
          ldsc4(pb0, slotB); ldsc4(pb1, slotB + 4);
          asm volatile("s_waitcnt vmcnt(0)"
                       : "+v"(pa0), "+v"(pa1), "+v"(pb0), "+v"(pb1) :: "memory");
          if (__float_as_uint(pa0.x) >= tgt && __float_as_uint(pb0.x) >= tgt)
            break;
          __builtin_amdgcn_s_sleep(2);
        }
        // buddy: masked out-softmax for step t-1 (fills flag-wait slack;
        // logits(t-1) were drained before the slot release).
        if (isbud)
          c_head_out(t - 1, bb2, mask, out, lgg + bb2 * NK, wred);
      } else {
        // k=0: slots valid from init / previous chunk; no poll.
        ldsc4(pa0, slotA); ldsc4(pa1, slotA + 4);
        ldsc4(pb0, slotB); ldsc4(pb1, slotB + 4);
        asm volatile("s_waitcnt vmcnt(0)"
                     : "+v"(pa0), "+v"(pa1), "+v"(pb0), "+v"(pb1) :: "memory");
      }
      asm volatile("s_waitcnt vmcnt(0)" : "+v"(xv) :: "memory");  // tie xv
      const float invS = 1.0f / pa0.y;
      vf4 as0, as1;
      as0.x = pa0.z; as0.y = pa0.w; as0.z = pa1.x; as0.w = pa1.y;
      as1.x = pb0.z; as1.y = pb0.w; as1.z = pb1.x; as1.w = pb1.y;
      ZERO16
      R16A(FMAROW, as0, wA, ks4 + 512)
      R16A(FMAROW, as1, wA, ks4 + 576)
      RED16
      // A0 = Sum W*e for (row rr, batch bbl); scale by 1/S (same batch).
      gbuf[rr][bbl] = partA + A0 * invS + xv;  // Xpre includes both biases
      GATES(c1r, h1cur)
    }
    // ---- prefetch phase-B ab (h2prev) BEFORE P1 arrive: the garrive drain
    // (vmcnt(0)) covers the h1 store AND these loads in one latency window.
    // (h2prev(t-1) visibility via the slot-release chain; garrive has no poll.)
    {
      const float* p2 = h2prev + (size_t)bbg * Hz + ks4;
      ldsc4(ab0, p2);       ldsc4(ab1, p2 + 64);  ldsc4(ab2, p2 + 128);
      ldsc4(ab3, p2 + 192); ldsc4(ab4, p2 + 256); ldsc4(ab5, p2 + 320);
      ldsc4(ab6, p2 + 384); ldsc4(ab7, p2 + 448);
    }
    const unsigned int gA = g;
    garrive(barg, gidx, gA); ++g;               // P1 arrive (h1cur published)

    // ============ Phase B: ab-half first, deferred P1 wait at boundary ====
    {
      ZERO16
      // ab data landed (garrive drained vmcnt(0)); compile-order tie only.
      FENCE8(0, ab0,ab1,ab2,ab3,ab4,ab5,ab6,ab7);
      R16A(FMAROW, ab0, wB, ks4 + 512)
      R16A(FMAROW, ab1, wB, ks4 + 576)
      R16A(FMAROW, ab2, wB, ks4 + 640)
      R16A(FMAROW, ab3, wB, ks4 + 704)
      R16A(FMAROW, ab4, wB, ks4 + 768)
      R16A(FMAROW, ab5, wB, ks4 + 832)
      R16A(FMAROW, ab6, wB, ks4 + 896)
      R16A(FMAROW, ab7, wB, ks4 + 960)
      RED16
      const float partB = A0;            // W_hh1*h2prev, reduced (1 reg)
      // ---- deferred P1 wait: single-level all-poll (1 RT, no bcast) ------
      if (tid < 128) {
        unsigned int* wsl = barg + tid * 16;
        while (__hip_atomic_load(wsl, __ATOMIC_RELAXED,
                                 __HIP_MEMORY_SCOPE_SYSTEM) < gA)
          __builtin_amdgcn_s_sleep(1);
      }
      __syncthreads();
      // ---- aa half (h1cur, now synced) -> loads into CARRIED ca regs -----
      const float* p1 = h1cur + (size_t)bbg * Hz + ks4;
      ldsc4(ca0, p1);       ldsc4(ca1, p1 + 64);  ldsc4(ca2, p1 + 128);
      ldsc4(ca3, p1 + 192); ldsc4(ca4, p1 + 256); ldsc4(ca5, p1 + 320);
      ldsc4(ca6, p1 + 384); ldsc4(ca7, p1 + 448);
      ZERO16
      FENCE8(0, ca0,ca1,ca2,ca3,ca4,ca5,ca6,ca7);
      R16A(FMAROW, ca0, wB, ks4 +   0)
      R16A(FMAROW, ca1, wB, ks4 +  64)
      R16A(FMAROW, ca2, wB, ks4 + 128)
      R16A(FMAROW, ca3, wB, ks4 + 192)
      R16A(FMAROW, ca4, wB, ks4 + 256)
      R16A(FMAROW, ca5, wB, ks4 + 320)
      R16A(FMAROW, ca6, wB, ks4 + 384)
      R16A(FMAROW, ca7, wB, ks4 + 448)
      RED16
      gbuf[rr][bbl] = A0 + partB + biasB[rr];
      GATES(c2r, h2cur)
    }
    const unsigned int gB = g;
    garrive(barg, gidx, gB); ++g;               // P2 arrive; workers sail on

    // ============ head bottom: sm-critical for step t (ca stays live) =====
    if (bid < 32) {
      // wait all group blocks arrived P2 (h2cur complete)
      if (tid < 128) {
        unsigned int* wsl = barg + tid * 16;
        while (__hip_atomic_load(wsl, __ATOMIC_RELAXED,
                                 __HIP_MEMORY_SCOPE_SYSTEM) < gB)
          __builtin_amdgcn_s_sleep(1);
      }
      __syncthreads();
      if (tid < 128) {
        vf4 v;
        ldsc4(v, h2cur + (size_t)hb * Hz + tid * 4);
        asm volatile("s_waitcnt vmcnt(0)" : "+v"(v) :: "memory");
        *(vf4*)&hsg[tid * 4] = v;
      }
      __syncthreads();
      c_head_crit(hsg, hb, W_out, b_out, esl, lgg + hb * NK, wred,
                  (unsigned int)(k + 1));
    }
  }

  // ===== epilogue: buddies emit out(t_last) after final slot release ======
  if (isbud) {
    if (tid == 0) {
      const unsigned int* fp = (const unsigned int*)(esl + (size_t)bb2 * 256);
      while (__hip_atomic_load(fp, __ATOMIC_RELAXED,
                               __HIP_MEMORY_SCOPE_SYSTEM) < (unsigned int)nsteps)
        __builtin_amdgcn_s_sleep(1);
    }
    __syncthreads();
    c_head_out(t0 + nsteps - 1, bb2, mask, out, lgg + bb2 * NK, wred);
  }

  // spill c-state for next chunk (no-op cost in full path)
  if (tid < 64) {
    const size_t ci = (size_t)(pg * 16 + cbl) * Hz + jg * 4 + cu;
    stsc1(c1g + ci, c1r);
    stsc1(c2g + ci, c2r);
  }
}

// ---------------------------------------------------------------------------
extern "C" void kernel_launch(void* const* d_in, const int* in_sizes, int n_in,
                              void* d_out, int out_size, void* d_ws, size_t ws_size,
                              hipStream_t stream) {
  (void)in_sizes; (void)n_in; (void)out_size;
  const float* hiddens = (const float*)d_in[0];
  const float* h_t     = (const float*)d_in[1];
  const float* c_t     = (const float*)d_in[2];
  const float* mask    = (const float*)d_in[3];
  const float* W_out   = (const float*)d_in[4];
  const float* b_out   = (const float*)d_in[5];
  const float* W_ih0   = (const float*)d_in[6];
  const float* W_hh0   = (const float*)d_in[7];
  const float* b_ih0   = (const float*)d_in[8];
  const float* b_hh0   = (const float*)d_in[9];
  const float* W_ih1   = (const float*)d_in[10];
  const float* W_hh1   = (const float*)d_in[11];
  const float* b_ih1   = (const float*)d_in[12];
  const float* b_hh1   = (const float*)d_in[13];
  float* out = (float*)d_out;

  unsigned int* bar = (unsigned int*)d_ws;                 // 32 KB (memset/chunk)
  float* base = (float*)((char*)d_ws + 32768);
  float* h1g  = base;                                      // 2*BH
  float* h2g  = h1g + 2 * BH;                              // 2*BH
  float* esl  = h2g + 2 * BH;                              // Bz*256 packed slots
  float* c1g  = esl + Bz * 256;                            // BH
  float* c2g  = c1g + BH;                                  // BH
  float* lgg  = c2g + BH;                                  // Bz*NK raw logits
  float* Xpre = lgg + Bz * NK;                             // full: 2048*8192

  const size_t fullNeed = 32768 +
      (size_t)(4 * BH + Bz * 256 + 2 * BH + Bz * NK + 2048 * 8192) * 4;
  const bool full = ws_size >= fullNeed;
  const int NCH    = full ? 1 : 16;
  const int CH     = full ? Tz : 16;
  const int cstr   = full ? (Tz * 32) : (16 * 32);
  const int cTiles = cstr / 64;

  for (int c = 0; c < NCH; ++c) {
    const int t0 = c * CH;
    hipMemsetAsync(bar, 0, 32768, stream);
    hipLaunchKernelGGL(xpre_kernel, dim3(32 * cTiles), dim3(256), 0, stream,
                       hiddens, W_ih0, b_ih0, b_hh0, Xpre, t0, cTiles, cstr);
    int nsteps = CH, cs = cstr, tt0 = t0;
    void* ka[] = { (void*)&hiddens, (void*)&h_t, (void*)&c_t, (void*)&mask,
                   (void*)&W_out, (void*)&b_out, (void*)&W_ih0, (void*)&W_hh0,
                   (void*)&W_ih1, (void*)&W_hh1, (void*)&b_ih1, (void*)&b_hh1,
                   (void*)&Xpre, (void*)&out, (void*)&h1g, (void*)&h2g,
                   (void*)&esl, (void*)&c1g, (void*)&c2g, (void*)&lgg,
                   (void*)&bar, (void*)&tt0, (void*)&nsteps, (void*)&cs };
    hipError_t err = hipLaunchCooperativeKernel((void*)seq_kernel, dim3(NBLK),
                                                dim3(256), ka, 0, stream);
    if (err != hipSuccess) {
      // fallback: plain launch; 256 blocks at 1 block/CU are co-resident.
      hipLaunchKernelGGL(seq_kernel, dim3(NBLK), dim3(256), 0, stream,
                         hiddens, h_t, c_t, mask, W_out, b_out, W_ih0, W_hh0,
                         W_ih1, W_hh1, b_ih1, b_hh1, Xpre, out,
                         h1g, h2g, esl, c1g, c2g, lgg, bar, tt0, nsteps, cs);
    }
  }
}

// Round 17
// 5191.335 us; speedup vs baseline: 1.0392x; 1.0392x over previous
//
#include <hip/hip_runtime.h>
#include <cstdint>
#include <cstddef>

// ---------------------------------------------------------------------------
// TaggingFNNDecoder round 24.
// r23 post-mortem: packed e-slot self-poll regressed (+1us/step; all 64
// lanes polling 2x16B slots, wave exits at slowest lane) -- falsifier fired,
// piece 2 reverted. Piece 1 (all-poll P1) was never isolated.
// r24 = r22 (best, ~4740us typ) + ONE change: deferred P1 wait becomes a
// single-level all-poll (tid<128 poll the 128 arrive slots, s_sleep
// throttled, 1 LLC RT) replacing master-poll -> bcast (2 serialized RTs).
// The r8 indictment of all-poll was overturned in r9 (traffic was register
// spill); this poll sits at the proven register-boundary shape.
// Everything else byte-identical to r22.
// Falsifier: regression vs r22 => final answer is r22.
// ---------------------------------------------------------------------------

#define Bz   32
#define Tz   256
#define Dz   1024
#define Hz   512
#define NK   128
#define IN0  1152
#define NBLK 256
#define BH   16384      // Bz*Hz

typedef float vf4 __attribute__((ext_vector_type(4)));
typedef unsigned long long ull;

__device__ __forceinline__ void ldsc4(vf4& d, const float* p) {
  asm volatile("global_load_dwordx4 %0, %1, off sc0 sc1" : "=v"(d) : "v"(p));
}
__device__ __forceinline__ void ldg1(float& d, const float* p) {
  asm volatile("global_load_dword %0, %1, off" : "=v"(d) : "v"(p));
}
__device__ __forceinline__ float ldsc1f(const float* p) {
  float d;
  asm volatile("global_load_dword %0, %1, off sc0 sc1" : "=v"(d) : "v"(p));
  asm volatile("s_waitcnt vmcnt(0)" : "+v"(d) :: "memory");
  return d;
}
__device__ __forceinline__ void stsc1(float* p, float v) {
  asm volatile("global_store_dword %0, %1, off sc0 sc1" :: "v"(p), "v"(v) : "memory");
}
__device__ __forceinline__ void stsc2u(ull* p, ull v) {
  asm volatile("global_store_dwordx2 %0, %1, off sc0 sc1" :: "v"(p), "v"(v) : "memory");
}
#define FENCE8(c, a0,a1,a2,a3,a4,a5,a6,a7) \
  asm volatile("s_waitcnt vmcnt(" #c ")" : "+v"(a0),"+v"(a1),"+v"(a2),"+v"(a3), \
               "+v"(a4),"+v"(a5),"+v"(a6),"+v"(a7) :: "memory")

// NOTE: macro params must not collide with vector member names x/y/z/w.
#define FMA4(acc, W_, A_) \
  acc = fmaf((W_).x,(A_).x, fmaf((W_).y,(A_).y, fmaf((W_).z,(A_).z, fmaf((W_).w,(A_).w,(acc)))))

__device__ __forceinline__ float sigf(float x) { return 1.0f / (1.0f + expf(-x)); }

// ---------------- full barrier (prologue only) -----------------------------
__device__ __forceinline__ void gbar(unsigned int* slots, unsigned int* bcast,
                                     int gidx, bool master, unsigned int g) {
  asm volatile("s_waitcnt vmcnt(0)" ::: "memory");
  __syncthreads();
  if (threadIdx.x == 0)
    __hip_atomic_store(slots + gidx * 16, g,
                       __ATOMIC_RELAXED, __HIP_MEMORY_SCOPE_SYSTEM);
  if (master) {
    if (threadIdx.x < 128) {
      unsigned int* wsl = slots + threadIdx.x * 16;
      while (__hip_atomic_load(wsl, __ATOMIC_RELAXED, __HIP_MEMORY_SCOPE_SYSTEM) < g)
        __builtin_amdgcn_s_sleep(1);
    }
    __syncthreads();
    if (threadIdx.x == 0) {
      asm volatile("s_waitcnt vmcnt(0)" ::: "memory");
      __hip_atomic_store(bcast, g, __ATOMIC_RELAXED, __HIP_MEMORY_SCOPE_SYSTEM);
    }
  } else if (threadIdx.x == 0) {
    while (__hip_atomic_load(bcast, __ATOMIC_RELAXED, __HIP_MEMORY_SCOPE_SYSTEM) < g)
      __builtin_amdgcn_s_sleep(1);
  }
  __syncthreads();
}

// ---------------- arrive-only: drain (stores+loads), publish slot ----------
__device__ __forceinline__ void garrive(unsigned int* slots, int gidx,
                                        unsigned int g) {
  asm volatile("s_waitcnt vmcnt(0)" ::: "memory");
  __syncthreads();
  if (threadIdx.x == 0)
    __hip_atomic_store(slots + gidx * 16, g,
                       __ATOMIC_RELAXED, __HIP_MEMORY_SCOPE_SYSTEM);
}

// 16-row FMA over all rows r for one act vf4 from LDS base BASE at col KOFF.
#define FMAROW(r, AV, BASE, KOFF) \
  { vf4 wv = *(const vf4*)&BASE[r][KOFF]; FMA4(A##r, wv, AV); }
#define R16A(OP, AV, BASE, KOFF) \
  OP(0,AV,BASE,KOFF) OP(1,AV,BASE,KOFF) OP(2,AV,BASE,KOFF) OP(3,AV,BASE,KOFF) \
  OP(4,AV,BASE,KOFF) OP(5,AV,BASE,KOFF) OP(6,AV,BASE,KOFF) OP(7,AV,BASE,KOFF) \
  OP(8,AV,BASE,KOFF) OP(9,AV,BASE,KOFF) OP(10,AV,BASE,KOFF) OP(11,AV,BASE,KOFF) \
  OP(12,AV,BASE,KOFF) OP(13,AV,BASE,KOFF) OP(14,AV,BASE,KOFF) OP(15,AV,BASE,KOFF)

// 4-stage value-halving butterfly over 16-lane ks groups; after it, lane ks's
// A0 holds the full k-sum of row rev4(ks). (r6-validated scheme.)
#define RED16 { \
  { const bool hi = (ks & 1) != 0; \
    float s0=hi?A0:A8, s1=hi?A1:A9, s2=hi?A2:A10, s3=hi?A3:A11; \
    float s4=hi?A4:A12, s5=hi?A5:A13, s6=hi?A6:A14, s7=hi?A7:A15; \
    float k0=hi?A8:A0, k1=hi?A9:A1, k2=hi?A10:A2, k3=hi?A11:A3; \
    float k4=hi?A12:A4, k5=hi?A13:A5, k6=hi?A14:A6, k7=hi?A15:A7; \
    A0=k0+__shfl_xor(s0,1,64); A1=k1+__shfl_xor(s1,1,64); \
    A2=k2+__shfl_xor(s2,1,64); A3=k3+__shfl_xor(s3,1,64); \
    A4=k4+__shfl_xor(s4,1,64); A5=k5+__shfl_xor(s5,1,64); \
    A6=k6+__shfl_xor(s6,1,64); A7=k7+__shfl_xor(s7,1,64); } \
  { const bool hi = (ks & 2) != 0; \
    float s0=hi?A0:A4, s1=hi?A1:A5, s2=hi?A2:A6, s3=hi?A3:A7; \
    float k0=hi?A4:A0, k1=hi?A5:A1, k2=hi?A6:A2, k3=hi?A7:A3; \
    A0=k0+__shfl_xor(s0,2,64); A1=k1+__shfl_xor(s1,2,64); \
    A2=k2+__shfl_xor(s2,2,64); A3=k3+__shfl_xor(s3,2,64); } \
  { const bool hi = (ks & 4) != 0; \
    float s0=hi?A0:A2, s1=hi?A1:A3; float k0=hi?A2:A0, k1=hi?A3:A1; \
    A0=k0+__shfl_xor(s0,4,64); A1=k1+__shfl_xor(s1,4,64); } \
  { const bool hi = (ks & 8) != 0; \
    float s0=hi?A0:A1; float k0=hi?A1:A0; \
    A0=k0+__shfl_xor(s0,8,64); } }

#define ZERO16 A0=0.f;A1=0.f;A2=0.f;A3=0.f;A4=0.f;A5=0.f;A6=0.f;A7=0.f; \
               A8=0.f;A9=0.f;A10=0.f;A11=0.f;A12=0.f;A13=0.f;A14=0.f;A15=0.f;

// gate nonlinearity + h write. tid<64: cu=tid&3 (unit), cbl=tid>>2 (batch).
#define GATES(CREG, HDST) \
  __syncthreads(); \
  if (tid < 64) { \
    float gi = gbuf[cu][cbl],      gf = gbuf[4 + cu][cbl]; \
    float gg = gbuf[8 + cu][cbl],  go = gbuf[12 + cu][cbl]; \
    CREG = sigf(gf) * CREG + sigf(gi) * tanhf(gg); \
    stsc1(HDST + (size_t)(pg * 16 + cbl) * Hz + jg * 4 + cu, \
          sigf(go) * tanhf(CREG)); \
  }

// ---------------- head critical: GEMV + e/S via flag64 ---------------------
// Pair layout: n=tid>>1, kh=tid&1; shfl_xor(p,1) completes the dot -> no
// cpart LDS pass. e=exp(logit) stored UNNORMALIZED to smg immediately; raw
// logit to lgg; S reduced while stores drain; flag64 = {fval, bits(S)} in
// one store. sSb (persistent) also gets S for chunk-boundary k=0 reads.
__device__ void c_head_crit(const float* src, int bb,
                            const float* __restrict__ W_out,
                            const float* __restrict__ b_out,
                            float* __restrict__ smg, float* __restrict__ lggb,
                            float* __restrict__ sSb, float* wred,
                            ull* smflag64, unsigned int fval) {
  const int tid = threadIdx.x;
  const int n = tid >> 1, kh = tid & 1;
  float p = 0.0f;
  const float* w  = W_out + (size_t)n * Hz + kh * 256;
  const float* s2 = src + kh * 256;
  #pragma unroll 8
  for (int k = 0; k < 256; k += 4) {
    vf4 sv = *(const vf4*)(s2 + k);
    vf4 wv = *(const vf4*)(w + k);
    p += sv.x * wv.x + sv.y * wv.y + sv.z * wv.z + sv.w * wv.w;
  }
  p += __shfl_xor(p, 1, 64);            // both lanes of the pair: full dot
  float logit = p + b_out[n];
  float e = expf(logit);
  if (kh == 0) {
    stsc1(lggb + n, logit);             // raw logits for buddy out-softmax
    stsc1(smg + bb * NK + n, e);        // unnormalized e, stored EARLY
  }
  // S = sum_n e  (each n appears twice across lanes -> *0.5)
  float s = e;
  #pragma unroll
  for (int off = 32; off >= 1; off >>= 1) s += __shfl_xor(s, off);
  if ((tid & 63) == 0) wred[tid >> 6] = s;
  __syncthreads();
  float S = (wred[0] + wred[1] + wred[2] + wred[3]) * 0.5f;
  if (tid == 0) stsc1(sSb, S);          // persistent S (chunk boundary)
  asm volatile("s_waitcnt vmcnt(0)" ::: "memory");
  __syncthreads();
  if (fval && tid == 0) {
    ull v = ((ull)fval << 32) | (ull)__float_as_uint(S);
    stsc2u(smflag64, v);
  }
}

// ---------------- buddy: masked output softmax from global logits ----------
__device__ void c_head_out(int t, int bb, const float* __restrict__ mask,
                           float* __restrict__ out,
                           const float* __restrict__ lggb, float* wred) {
  const int tid = threadIdx.x;
  const int n = tid & 127;
  float lg = 0.0f;
  if (tid < 128)
    lg = __hip_atomic_load(lggb + n, __ATOMIC_RELAXED, __HIP_MEMORY_SCOPE_SYSTEM);
  float mk = (tid < 128) ? mask[bb * Tz + t] : 1.0f;
  float lm = (tid < 128) ? (lg + (1.0f - mk) * (-1e32f)) : -3.0e38f;
  float m2 = lm;
  #pragma unroll
  for (int off = 32; off >= 1; off >>= 1) m2 = fmaxf(m2, __shfl_xor(m2, off));
  if ((tid & 63) == 0 && tid < 128) wred[4 + (tid >> 6)] = m2;
  __syncthreads();
  float M2 = fmaxf(wred[4], wred[5]);
  float e2 = (tid < 128) ? expf(lm - M2) : 0.0f;
  float s2r = e2;
  #pragma unroll
  for (int off = 32; off >= 1; off >>= 1) s2r += __shfl_xor(s2r, off);
  if ((tid & 63) == 0 && tid < 128) wred[6 + (tid >> 6)] = s2r;
  __syncthreads();
  float S2 = wred[6] + wred[7];
  if (tid < 128) out[((size_t)bb * Tz + t) * NK + n] = e2 / S2;
}

// ---------------- Xpre GEMM (r1's verified kernel, generalized) -----------
// Xpre[n][(t-t0)*32+b] = sum_k hiddens[b][t][k]*W_ih0[n][k] + b_ih0[n]+b_hh0[n]
__global__ void __launch_bounds__(256)
xpre_kernel(const float* __restrict__ hiddens, const float* __restrict__ W_ih0,
            const float* __restrict__ b_ih0, const float* __restrict__ b_hh0,
            float* __restrict__ Xpre, int t0, int colTiles, int cstride) {
  __shared__ float Ws[16][64];
  __shared__ float Hs[16][64];
  const int tid = threadIdx.x;
  const int bx = blockIdx.x % colTiles;
  const int by = blockIdx.x / colTiles;
  const int n0 = by * 64, c0 = bx * 64;
  const int tx = tid & 15, ty = tid >> 4;
  const int ldn = tid >> 2;
  const int ldk = (tid & 3) * 4;

  const int bb = ldn & 31;
  const int tt = t0 + (c0 >> 5) + (ldn >> 5);
  const float* hsrc = hiddens + ((size_t)bb * Tz + tt) * Dz + ldk;
  const float* wsrc = W_ih0 + (size_t)(n0 + ldn) * IN0 + ldk;

  float acc[4][4] = {};
  vf4 wv = *(const vf4*)(wsrc);
  vf4 hv = *(const vf4*)(hsrc);
  for (int k0 = 0; k0 < Dz; k0 += 16) {
    __syncthreads();
    Ws[ldk + 0][ldn] = wv.x; Ws[ldk + 1][ldn] = wv.y;
    Ws[ldk + 2][ldn] = wv.z; Ws[ldk + 3][ldn] = wv.w;
    Hs[ldk + 0][ldn] = hv.x; Hs[ldk + 1][ldn] = hv.y;
    Hs[ldk + 2][ldn] = hv.z; Hs[ldk + 3][ldn] = hv.w;
    __syncthreads();
    if (k0 + 16 < Dz) {
      wv = *(const vf4*)(wsrc + k0 + 16);
      hv = *(const vf4*)(hsrc + k0 + 16);
    }
    #pragma unroll
    for (int k = 0; k < 16; ++k) {
      vf4 a4 = *(const vf4*)&Ws[k][ty * 4];
      vf4 b4 = *(const vf4*)&Hs[k][tx * 4];
      acc[0][0] += a4.x * b4.x; acc[0][1] += a4.x * b4.y; acc[0][2] += a4.x * b4.z; acc[0][3] += a4.x * b4.w;
      acc[1][0] += a4.y * b4.x; acc[1][1] += a4.y * b4.y; acc[1][2] += a4.y * b4.z; acc[1][3] += a4.y * b4.w;
      acc[2][0] += a4.z * b4.x; acc[2][1] += a4.z * b4.y; acc[2][2] += a4.z * b4.z; acc[2][3] += a4.z * b4.w;
      acc[3][0] += a4.w * b4.x; acc[3][1] += a4.w * b4.y; acc[3][2] += a4.w * b4.z; acc[3][3] += a4.w * b4.w;
    }
  }
  #pragma unroll
  for (int i = 0; i < 4; ++i) {
    int n = n0 + ty * 4 + i;
    float bi = b_ih0[n] + b_hh0[n];
    vf4 v; v.x = acc[i][0] + bi; v.y = acc[i][1] + bi;
    v.z = acc[i][2] + bi; v.w = acc[i][3] + bi;
    *(vf4*)(Xpre + (size_t)n * cstride + c0 + tx * 4) = v;
  }
}

// ---------------- the persistent kernel -----------------------------------
__global__ void __launch_bounds__(256)
seq_kernel(const float* __restrict__ hiddens,
           const float* __restrict__ h_t, const float* __restrict__ c_t,
           const float* __restrict__ mask,
           const float* __restrict__ W_out, const float* __restrict__ b_out,
           const float* __restrict__ W_ih0, const float* __restrict__ W_hh0,
           const float* __restrict__ W_ih1, const float* __restrict__ W_hh1,
           const float* __restrict__ b_ih1, const float* __restrict__ b_hh1,
           const float* __restrict__ Xpre, float* __restrict__ out,
           float* __restrict__ h1g, float* __restrict__ h2g,
           float* __restrict__ smg, float* __restrict__ c1g, float* __restrict__ c2g,
           float* __restrict__ lgg, float* __restrict__ sSg,
           unsigned int* bar, int t0, int nsteps, int cstride) {
  __shared__ float wA[16][640];     // [W_hh0(512) | W_ih0 sm-cols(128)]
  __shared__ float wB[16][1024];    // [W_ih1(512) | W_hh1(512)]
  __shared__ float gbuf[16][17];
  __shared__ float biasB[16];
  __shared__ float hsg[512];
  __shared__ float wred[8];
  __shared__ float sSl[16];         // per-batch 1/S for this pg group

  const int tid = threadIdx.x;
  const int bid = blockIdx.x;
  const int jg  = bid >> 1;          // j-group 0..127 (4 hidden units)
  const int pg  = bid & 1;           // batch-group 0..1 (16 batches)
  const int ks  = tid & 15;          // k-slice 0..15
  const int bbl = tid >> 4;          // local batch 0..15
  const int bbg = pg * 16 + bbl;     // global batch
  const int ks4 = ks * 4;
  const int cu  = tid & 3, cbl = tid >> 2;   // GATES mapping (tid<64)
  const int rr  = ((ks & 1) << 3) | ((ks & 2) << 1) | ((ks & 4) >> 1) | ((ks & 8) >> 3);
  const int rowG = ((rr >> 2) * Hz) + jg * 4 + (rr & 3);   // butterfly-out row
  // head blocks: bid<32; batch remapped into the block's own pg-group.
  const int hb = ((bid & 1) << 4) | (bid >> 1);
  // buddy blocks: bid in [32,64); masked out-softmax for batch bb2 (own pg).
  const bool isbud = (bid >= 32 && bid < 64);
  const int  bb2   = isbud ? (((bid & 1) << 4) | ((bid >> 1) - 16)) : 0;

  // bar layout (uints): [0..2047] g0 slots (64B stride), [2048..4095] g1
  // slots, [4096 + pg*16] bcast words, [4608 + b*16] sm flag64s (8B-aligned).
  unsigned int* barg = bar + pg * 2048;
  unsigned int* bcst = bar + 4096 + pg * 16;
  unsigned int* smf  = bar + 4608;
  const int  gidx    = bid >> 1;            // slot index within group
  const bool gmaster = (gidx == 127);       // bid 254 / 255

  // ---- one-time: weights -> LDS (block-private rows, read-only source) ----
  #pragma clang loop unroll(disable)
  for (int r = 0; r < 16; ++r) {
    const int row = ((r >> 2) * Hz) + jg * 4 + (r & 3);
    if (tid * 4 < 512)
      *(vf4*)&wA[r][tid * 4] = *(const vf4*)(W_hh0 + (size_t)row * Hz + tid * 4);
    if (tid * 4 < 128)
      *(vf4*)&wA[r][512 + tid * 4] = *(const vf4*)(W_ih0 + (size_t)row * IN0 + 1024 + tid * 4);
    if (tid * 4 < 512) {
      *(vf4*)&wB[r][tid * 4]       = *(const vf4*)(W_ih1 + (size_t)row * Hz + tid * 4);
      *(vf4*)&wB[r][512 + tid * 4] = *(const vf4*)(W_hh1 + (size_t)row * Hz + tid * 4);
    }
  }
  if (tid < 16) {
    const int row = ((tid >> 2) * Hz) + jg * 4 + (tid & 3);
    biasB[tid] = b_ih1[row] + b_hh1[row];
  }

  // ---- c-state in registers (tid<64: unit cu, batch cbl) ----
  float c1r = 0.0f, c2r = 0.0f;
  if (tid < 64) {
    const size_t ci = (size_t)(pg * 16 + cbl) * Hz + jg * 4 + cu;
    if (t0 == 0) { c1r = c_t[ci]; c2r = c_t[BH + ci]; }
    else         { c1r = c1g[ci]; c2r = c2g[ci]; }
  }

  if (t0 == 0) {
    // stage h_t into parity-1 h buffers; compute e/S(-1)
    if (bid < 32 && tid < 128) {
      vf4 v1 = *(const vf4*)(h_t + (size_t)hb * Hz + tid * 4);
      vf4 v2 = *(const vf4*)(h_t + BH + (size_t)hb * Hz + tid * 4);
      float* d1 = h1g + BH + (size_t)hb * Hz + tid * 4;
      float* d2 = h2g + BH + (size_t)hb * Hz + tid * 4;
      stsc1(d1, v1.x); stsc1(d1 + 1, v1.y); stsc1(d1 + 2, v1.z); stsc1(d1 + 3, v1.w);
      stsc1(d2, v2.x); stsc1(d2 + 1, v2.y); stsc1(d2 + 2, v2.z); stsc1(d2 + 3, v2.w);
    }
    if (bid < 32) {
      if (tid < 128)
        *(vf4*)&hsg[tid * 4] = *(const vf4*)(hiddens + (size_t)hb * Tz * Dz + tid * 4);
      __syncthreads();
      c_head_crit(hsg, hb, W_out, b_out, smg, lgg + hb * NK, sSg + hb, wred,
                  (ull*)(smf + hb * 16), 0u);
    }
  }
  __syncthreads();
  unsigned int g = 1;
  gbar(barg, bcst, gidx, gmaster, g); ++g;      // g is now 2

  // ---- loop-carried phase-A operands: ca = h1prev(t) [= prev iter's aa] --
  vf4 ca0,ca1,ca2,ca3,ca4,ca5,ca6,ca7;
  {
    const float* hp = h1g + ((t0 + 1) & 1) * BH + (size_t)bbg * Hz + ks4;
    ldsc4(ca0, hp);        ldsc4(ca1, hp + 64);  ldsc4(ca2, hp + 128);
    ldsc4(ca3, hp + 192);  ldsc4(ca4, hp + 256); ldsc4(ca5, hp + 320);
    ldsc4(ca6, hp + 384);  ldsc4(ca7, hp + 448);
    FENCE8(0, ca0,ca1,ca2,ca3,ca4,ca5,ca6,ca7);
  }

  #pragma clang loop unroll(disable)
  for (int k = 0; k < nsteps; ++k) {
    const int t = t0 + k;
    float*       h1cur  = h1g + (t & 1) * BH;
    const float* h2prev = h2g + ((t + 1) & 1) * BH;
    float*       h2cur  = h2g + (t & 1) * BH;
    float A0,A1,A2,A3,A4,A5,A6,A7,A8,A9,A10,A11,A12,A13,A14,A15;
    vf4 ab0,ab1,ab2,ab3,ab4,ab5,ab6,ab7;   // phase-B h2prev operands

    // ============ Phase A: layer-0 gates (ah = carried ca regs) ===========
    {
      vf4 as0,as1;
      float xv;
      ldg1(xv, Xpre + (size_t)rowG * cstride + k * 32 + bbg);
      ZERO16
      R16A(FMAROW, ca0, wA, ks4 +   0)
      R16A(FMAROW, ca1, wA, ks4 +  64)
      R16A(FMAROW, ca2, wA, ks4 + 128)
      R16A(FMAROW, ca3, wA, ks4 + 192)
      R16A(FMAROW, ca4, wA, ks4 + 256)
      R16A(FMAROW, ca5, wA, ks4 + 320)
      R16A(FMAROW, ca6, wA, ks4 + 384)
      R16A(FMAROW, ca7, wA, ks4 + 448)
      RED16
      const float partA = A0;            // ah contribution, reduced (1 reg)
      // ---- acquire e/S(t-1): tid<16 poll flag64 {cnt,S} (tiny live set) --
      if (k > 0) {
        const unsigned int tgt = (unsigned int)k;
        if (tid < 16) {
          const ull* fp = (const ull*)(smf + (pg * 16 + tid) * 16);
          ull v;
          for (;;) {
            v = __hip_atomic_load(fp, __ATOMIC_RELAXED, __HIP_MEMORY_SCOPE_SYSTEM);
            if ((unsigned int)(v >> 32) >= tgt) break;
            __builtin_amdgcn_s_sleep(1);
          }
          sSl[tid] = 1.0f / __uint_as_float((unsigned int)v);
        }
        __syncthreads();
        // buddy: masked out-softmax for step t-1 (fills flag-wait slack;
        // logits(t-1) were drained before flag k was released).
        if (isbud)
          c_head_out(t - 1, bb2, mask, out, lgg + bb2 * NK, wred);
      } else {
        if (tid < 16) sSl[tid] = 1.0f / ldsc1f(sSg + pg * 16 + tid);
        __syncthreads();
      }
      const float* sp = smg + (size_t)bbg * NK + ks4;
      ldsc4(as0, sp);        ldsc4(as1, sp + 64);
      ZERO16
      asm volatile("s_waitcnt vmcnt(0)" : "+v"(as0), "+v"(as1), "+v"(xv) :: "memory");
      R16A(FMAROW, as0, wA, ks4 + 512)
      R16A(FMAROW, as1, wA, ks4 + 576)
      RED16
      // A0 = Sum W*e for (row rr, batch bbl); scale by 1/S at the end.
      gbuf[rr][bbl] = partA + A0 * sSl[bbl] + xv;  // Xpre includes biases
      GATES(c1r, h1cur)
    }
    // ---- prefetch phase-B ab (h2prev) BEFORE P1 arrive: the garrive drain
    // (vmcnt(0)) covers the h1 store AND these loads in one latency window.
    // (h2prev(t-1) visibility via the flag chain; garrive has no poll.)
    {
      const float* p2 = h2prev + (size_t)bbg * Hz + ks4;
      ldsc4(ab0, p2);       ldsc4(ab1, p2 + 64);  ldsc4(ab2, p2 + 128);
      ldsc4(ab3, p2 + 192); ldsc4(ab4, p2 + 256); ldsc4(ab5, p2 + 320);
      ldsc4(ab6, p2 + 384); ldsc4(ab7, p2 + 448);
    }
    const unsigned int gA = g;
    garrive(barg, gidx, gA); ++g;               // P1 arrive (h1cur published)

    // ============ Phase B: ab-half first, deferred P1 wait at boundary ====
    {
      ZERO16
      // ab data landed (garrive drained vmcnt(0)); compile-order tie only.
      FENCE8(0, ab0,ab1,ab2,ab3,ab4,ab5,ab6,ab7);
      R16A(FMAROW, ab0, wB, ks4 + 512)
      R16A(FMAROW, ab1, wB, ks4 + 576)
      R16A(FMAROW, ab2, wB, ks4 + 640)
      R16A(FMAROW, ab3, wB, ks4 + 704)
      R16A(FMAROW, ab4, wB, ks4 + 768)
      R16A(FMAROW, ab5, wB, ks4 + 832)
      R16A(FMAROW, ab6, wB, ks4 + 896)
      R16A(FMAROW, ab7, wB, ks4 + 960)
      RED16
      const float partB = A0;            // W_hh1*h2prev, reduced (1 reg)
      // ---- deferred P1 wait: single-level all-poll (1 RT, no bcast) ------
      if (tid < 128) {
        unsigned int* wsl = barg + tid * 16;
        while (__hip_atomic_load(wsl, __ATOMIC_RELAXED,
                                 __HIP_MEMORY_SCOPE_SYSTEM) < gA)
          __builtin_amdgcn_s_sleep(1);
      }
      __syncthreads();
      // ---- aa half (h1cur, now synced) -> loads into CARRIED ca regs -----
      const float* p1 = h1cur + (size_t)bbg * Hz + ks4;
      ldsc4(ca0, p1);       ldsc4(ca1, p1 + 64);  ldsc4(ca2, p1 + 128);
      ldsc4(ca3, p1 + 192); ldsc4(ca4, p1 + 256); ldsc4(ca5, p1 + 320);
      ldsc4(ca6, p1 + 384); ldsc4(ca7, p1 + 448);
      ZERO16
      FENCE8(0, ca0,ca1,ca2,ca3,ca4,ca5,ca6,ca7);
      R16A(FMAROW, ca0, wB, ks4 +   0)
      R16A(FMAROW, ca1, wB, ks4 +  64)
      R16A(FMAROW, ca2, wB, ks4 + 128)
      R16A(FMAROW, ca3, wB, ks4 + 192)
      R16A(FMAROW, ca4, wB, ks4 + 256)
      R16A(FMAROW, ca5, wB, ks4 + 320)
      R16A(FMAROW, ca6, wB, ks4 + 384)
      R16A(FMAROW, ca7, wB, ks4 + 448)
      RED16
      gbuf[rr][bbl] = A0 + partB + biasB[rr];
      GATES(c2r, h2cur)
    }
    const unsigned int gB = g;
    garrive(barg, gidx, gB); ++g;               // P2 arrive; workers sail on

    // ============ head bottom: sm-critical for step t (ca stays live) =====
    if (bid < 32) {
      // wait all group blocks arrived P2 (h2cur complete)
      if (tid < 128) {
        unsigned int* wsl = barg + tid * 16;
        while (__hip_atomic_load(wsl, __ATOMIC_RELAXED,
                                 __HIP_MEMORY_SCOPE_SYSTEM) < gB)
          __builtin_amdgcn_s_sleep(1);
      }
      __syncthreads();
      if (tid < 128) {
        vf4 v;
        ldsc4(v, h2cur + (size_t)hb * Hz + tid * 4);
        asm volatile("s_waitcnt vmcnt(0)" : "+v"(v) :: "memory");
        *(vf4*)&hsg[tid * 4] = v;
      }
      __syncthreads();
      c_head_crit(hsg, hb, W_out, b_out, smg, lgg + hb * NK, sSg + hb, wred,
                  (ull*)(smf + hb * 16), (unsigned int)(k + 1));
    }
  }

  // ===== epilogue: buddies emit out(t_last) after final flag ==============
  if (isbud) {
    if (tid == 0) {
      const ull* fp = (const ull*)(smf + bb2 * 16);
      while ((unsigned int)(__hip_atomic_load(fp, __ATOMIC_RELAXED,
                              __HIP_MEMORY_SCOPE_SYSTEM) >> 32) < (unsigned int)nsteps)
        __builtin_amdgcn_s_sleep(1);
    }
    __syncthreads();
    c_head_out(t0 + nsteps - 1, bb2, mask, out, lgg + bb2 * NK, wred);
  }

  // spill c-state for next chunk (no-op cost in full path)
  if (tid < 64) {
    const size_t ci = (size_t)(pg * 16 + cbl) * Hz + jg * 4 + cu;
    stsc1(c1g + ci, c1r);
    stsc1(c2g + ci, c2r);
  }
}

// ---------------------------------------------------------------------------
extern "C" void kernel_launch(void* const* d_in, const int* in_sizes, int n_in,
                              void* d_out, int out_size, void* d_ws, size_t ws_size,
                              hipStream_t stream) {
  (void)in_sizes; (void)n_in; (void)out_size;
  const float* hiddens = (const float*)d_in[0];
  const float* h_t     = (const float*)d_in[1];
  const float* c_t     = (const float*)d_in[2];
  const float* mask    = (const float*)d_in[3];
  const float* W_out   = (const float*)d_in[4];
  const float* b_out   = (const float*)d_in[5];
  const float* W_ih0   = (const float*)d_in[6];
  const float* W_hh0   = (const float*)d_in[7];
  const float* b_ih0   = (const float*)d_in[8];
  const float* b_hh0   = (const float*)d_in[9];
  const float* W_ih1   = (const float*)d_in[10];
  const float* W_hh1   = (const float*)d_in[11];
  const float* b_ih1   = (const float*)d_in[12];
  const float* b_hh1   = (const float*)d_in[13];
  float* out = (float*)d_out;

  unsigned int* bar = (unsigned int*)d_ws;                 // 32 KB
  float* base = (float*)((char*)d_ws + 32768);
  float* h1g  = base;                                      // 2*BH
  float* h2g  = h1g + 2 * BH;                              // 2*BH
  float* smg  = h2g + 2 * BH;                              // Bz*NK (e values)
  float* c1g  = smg + Bz * NK;                             // BH
  float* c2g  = c1g + BH;                                  // BH
  float* lgg  = c2g + BH;                                  // Bz*NK raw logits
  float* sSg  = lgg + Bz * NK;                             // Bz persistent S
  float* Xpre = sSg + 64;                                  // full: 2048*8192

  const size_t fullNeed = 32768 + (size_t)(102400 + Bz * NK + 64 + 2048 * 8192) * 4;
  const bool full = ws_size >= fullNeed;
  const int NCH    = full ? 1 : 16;
  const int CH     = full ? Tz : 16;
  const int cstr   = full ? (Tz * 32) : (16 * 32);
  const int cTiles = cstr / 64;

  for (int c = 0; c < NCH; ++c) {
    const int t0 = c * CH;
    hipMemsetAsync(bar, 0, 32768, stream);
    hipLaunchKernelGGL(xpre_kernel, dim3(32 * cTiles), dim3(256), 0, stream,
                       hiddens, W_ih0, b_ih0, b_hh0, Xpre, t0, cTiles, cstr);
    int nsteps = CH, cs = cstr, tt0 = t0;
    void* ka[] = { (void*)&hiddens, (void*)&h_t, (void*)&c_t, (void*)&mask,
                   (void*)&W_out, (void*)&b_out, (void*)&W_ih0, (void*)&W_hh0,
                   (void*)&W_ih1, (void*)&W_hh1, (void*)&b_ih1, (void*)&b_hh1,
                   (void*)&Xpre, (void*)&out, (void*)&h1g, (void*)&h2g,
                   (void*)&smg, (void*)&c1g, (void*)&c2g, (void*)&lgg,
                   (void*)&sSg, (void*)&bar, (void*)&tt0, (void*)&nsteps,
                   (void*)&cs };
    hipError_t err = hipLaunchCooperativeKernel((void*)seq_kernel, dim3(NBLK),
                                                dim3(256), ka, 0, stream);
    if (err != hipSuccess) {
      // fallback: plain launch; 256 blocks at 1 block/CU are co-resident.
      hipLaunchKernelGGL(seq_kernel, dim3(NBLK), dim3(256), 0, stream,
                         hiddens, h_t, c_t, mask, W_out, b_out, W_ih0, W_hh0,
                         W_ih1, W_hh1, b_ih1, b_hh1, Xpre, out,
                         h1g, h2g, smg, c1g, c2g, lgg, sSg, bar, tt0, nsteps, cs);
    }
  }
}

// Round 19
// 5180.787 us; speedup vs baseline: 1.0413x; 1.0020x over previous
//
#include <hip/hip_runtime.h>
#include <cstdint>
#include <cstddef>

// ---------------------------------------------------------------------------
// TaggingFNNDecoder round 26 == r24 (FINAL, best verified).
// r25's pipelined 2-deep polls FAILED correctness (absmax 468) -- reverted
// per pre-commitment. r24 is the stable optimum: passed at dur_us 5191,
// seq ~4740us typ, VGPR 132, WRITE 83MB, absmax 6.1e-5.
// Session ladder (6131 -> 5191 us): 2 barriers/step + head fold + sm flag
// handoff (r16); buddy out-softmax offload (r18); register-boundary deferred
// P1 wait (r19); ab prefetch under arrive drain (r20); loop-carried h1
// operands (r21); fused e/S flag64 softmax handoff (r22); all-poll P1 (r24).
// Remaining ~18.5us/step is latency-bound on the sequential cross-XCD
// recurrence (HBM 0.7%, VALU 18.8%); r23/r25 showed further poll-latency
// surgery is neutral-to-harmful.
// ---------------------------------------------------------------------------

#define Bz   32
#define Tz   256
#define Dz   1024
#define Hz   512
#define NK   128
#define IN0  1152
#define NBLK 256
#define BH   16384      // Bz*Hz

typedef float vf4 __attribute__((ext_vector_type(4)));
typedef unsigned long long ull;

__device__ __forceinline__ void ldsc4(vf4& d, const float* p) {
  asm volatile("global_load_dwordx4 %0, %1, off sc0 sc1" : "=v"(d) : "v"(p));
}
__device__ __forceinline__ void ldg1(float& d, const float* p) {
  asm volatile("global_load_dword %0, %1, off" : "=v"(d) : "v"(p));
}
__device__ __forceinline__ float ldsc1f(const float* p) {
  float d;
  asm volatile("global_load_dword %0, %1, off sc0 sc1" : "=v"(d) : "v"(p));
  asm volatile("s_waitcnt vmcnt(0)" : "+v"(d) :: "memory");
  return d;
}
__device__ __forceinline__ void stsc1(float* p, float v) {
  asm volatile("global_store_dword %0, %1, off sc0 sc1" :: "v"(p), "v"(v) : "memory");
}
__device__ __forceinline__ void stsc2u(ull* p, ull v) {
  asm volatile("global_store_dwordx2 %0, %1, off sc0 sc1" :: "v"(p), "v"(v) : "memory");
}
#define FENCE8(c, a0,a1,a2,a3,a4,a5,a6,a7) \
  asm volatile("s_waitcnt vmcnt(" #c ")" : "+v"(a0),"+v"(a1),"+v"(a2),"+v"(a3), \
               "+v"(a4),"+v"(a5),"+v"(a6),"+v"(a7) :: "memory")

// NOTE: macro params must not collide with vector member names x/y/z/w.
#define FMA4(acc, W_, A_) \
  acc = fmaf((W_).x,(A_).x, fmaf((W_).y,(A_).y, fmaf((W_).z,(A_).z, fmaf((W_).w,(A_).w,(acc)))))

__device__ __forceinline__ float sigf(float x) { return 1.0f / (1.0f + expf(-x)); }

// ---------------- full barrier (prologue only) -----------------------------
__device__ __forceinline__ void gbar(unsigned int* slots, unsigned int* bcast,
                                     int gidx, bool master, unsigned int g) {
  asm volatile("s_waitcnt vmcnt(0)" ::: "memory");
  __syncthreads();
  if (threadIdx.x == 0)
    __hip_atomic_store(slots + gidx * 16, g,
                       __ATOMIC_RELAXED, __HIP_MEMORY_SCOPE_SYSTEM);
  if (master) {
    if (threadIdx.x < 128) {
      unsigned int* wsl = slots + threadIdx.x * 16;
      while (__hip_atomic_load(wsl, __ATOMIC_RELAXED, __HIP_MEMORY_SCOPE_SYSTEM) < g)
        __builtin_amdgcn_s_sleep(1);
    }
    __syncthreads();
    if (threadIdx.x == 0) {
      asm volatile("s_waitcnt vmcnt(0)" ::: "memory");
      __hip_atomic_store(bcast, g, __ATOMIC_RELAXED, __HIP_MEMORY_SCOPE_SYSTEM);
    }
  } else if (threadIdx.x == 0) {
    while (__hip_atomic_load(bcast, __ATOMIC_RELAXED, __HIP_MEMORY_SCOPE_SYSTEM) < g)
      __builtin_amdgcn_s_sleep(1);
  }
  __syncthreads();
}

// ---------------- arrive-only: drain (stores+loads), publish slot ----------
__device__ __forceinline__ void garrive(unsigned int* slots, int gidx,
                                        unsigned int g) {
  asm volatile("s_waitcnt vmcnt(0)" ::: "memory");
  __syncthreads();
  if (threadIdx.x == 0)
    __hip_atomic_store(slots + gidx * 16, g,
                       __ATOMIC_RELAXED, __HIP_MEMORY_SCOPE_SYSTEM);
}

// 16-row FMA over all rows r for one act vf4 from LDS base BASE at col KOFF.
#define FMAROW(r, AV, BASE, KOFF) \
  { vf4 wv = *(const vf4*)&BASE[r][KOFF]; FMA4(A##r, wv, AV); }
#define R16A(OP, AV, BASE, KOFF) \
  OP(0,AV,BASE,KOFF) OP(1,AV,BASE,KOFF) OP(2,AV,BASE,KOFF) OP(3,AV,BASE,KOFF) \
  OP(4,AV,BASE,KOFF) OP(5,AV,BASE,KOFF) OP(6,AV,BASE,KOFF) OP(7,AV,BASE,KOFF) \
  OP(8,AV,BASE,KOFF) OP(9,AV,BASE,KOFF) OP(10,AV,BASE,KOFF) OP(11,AV,BASE,KOFF) \
  OP(12,AV,BASE,KOFF) OP(13,AV,BASE,KOFF) OP(14,AV,BASE,KOFF) OP(15,AV,BASE,KOFF)

// 4-stage value-halving butterfly over 16-lane ks groups; after it, lane ks's
// A0 holds the full k-sum of row rev4(ks). (r6-validated scheme.)
#define RED16 { \
  { const bool hi = (ks & 1) != 0; \
    float s0=hi?A0:A8, s1=hi?A1:A9, s2=hi?A2:A10, s3=hi?A3:A11; \
    float s4=hi?A4:A12, s5=hi?A5:A13, s6=hi?A6:A14, s7=hi?A7:A15; \
    float k0=hi?A8:A0, k1=hi?A9:A1, k2=hi?A10:A2, k3=hi?A11:A3; \
    float k4=hi?A12:A4, k5=hi?A13:A5, k6=hi?A14:A6, k7=hi?A15:A7; \
    A0=k0+__shfl_xor(s0,1,64); A1=k1+__shfl_xor(s1,1,64); \
    A2=k2+__shfl_xor(s2,1,64); A3=k3+__shfl_xor(s3,1,64); \
    A4=k4+__shfl_xor(s4,1,64); A5=k5+__shfl_xor(s5,1,64); \
    A6=k6+__shfl_xor(s6,1,64); A7=k7+__shfl_xor(s7,1,64); } \
  { const bool hi = (ks & 2) != 0; \
    float s0=hi?A0:A4, s1=hi?A1:A5, s2=hi?A2:A6, s3=hi?A3:A7; \
    float k0=hi?A4:A0, k1=hi?A5:A1, k2=hi?A6:A2, k3=hi?A7:A3; \
    A0=k0+__shfl_xor(s0,2,64); A1=k1+__shfl_xor(s1,2,64); \
    A2=k2+__shfl_xor(s2,2,64); A3=k3+__shfl_xor(s3,2,64); } \
  { const bool hi = (ks & 4) != 0; \
    float s0=hi?A0:A2, s1=hi?A1:A3; float k0=hi?A2:A0, k1=hi?A3:A1; \
    A0=k0+__shfl_xor(s0,4,64); A1=k1+__shfl_xor(s1,4,64); } \
  { const bool hi = (ks & 8) != 0; \
    float s0=hi?A0:A1; float k0=hi?A1:A0; \
    A0=k0+__shfl_xor(s0,8,64); } }

#define ZERO16 A0=0.f;A1=0.f;A2=0.f;A3=0.f;A4=0.f;A5=0.f;A6=0.f;A7=0.f; \
               A8=0.f;A9=0.f;A10=0.f;A11=0.f;A12=0.f;A13=0.f;A14=0.f;A15=0.f;

// gate nonlinearity + h write. tid<64: cu=tid&3 (unit), cbl=tid>>2 (batch).
#define GATES(CREG, HDST) \
  __syncthreads(); \
  if (tid < 64) { \
    float gi = gbuf[cu][cbl],      gf = gbuf[4 + cu][cbl]; \
    float gg = gbuf[8 + cu][cbl],  go = gbuf[12 + cu][cbl]; \
    CREG = sigf(gf) * CREG + sigf(gi) * tanhf(gg); \
    stsc1(HDST + (size_t)(pg * 16 + cbl) * Hz + jg * 4 + cu, \
          sigf(go) * tanhf(CREG)); \
  }

// ---------------- head critical: GEMV + e/S via flag64 ---------------------
// Pair layout: n=tid>>1, kh=tid&1; shfl_xor(p,1) completes the dot -> no
// cpart LDS pass. e=exp(logit) stored UNNORMALIZED to smg immediately; raw
// logit to lgg; S reduced while stores drain; flag64 = {fval, bits(S)} in
// one store. sSb (persistent) also gets S for chunk-boundary k=0 reads.
__device__ void c_head_crit(const float* src, int bb,
                            const float* __restrict__ W_out,
                            const float* __restrict__ b_out,
                            float* __restrict__ smg, float* __restrict__ lggb,
                            float* __restrict__ sSb, float* wred,
                            ull* smflag64, unsigned int fval) {
  const int tid = threadIdx.x;
  const int n = tid >> 1, kh = tid & 1;
  float p = 0.0f;
  const float* w  = W_out + (size_t)n * Hz + kh * 256;
  const float* s2 = src + kh * 256;
  #pragma unroll 8
  for (int k = 0; k < 256; k += 4) {
    vf4 sv = *(const vf4*)(s2 + k);
    vf4 wv = *(const vf4*)(w + k);
    p += sv.x * wv.x + sv.y * wv.y + sv.z * wv.z + sv.w * wv.w;
  }
  p += __shfl_xor(p, 1, 64);            // both lanes of the pair: full dot
  float logit = p + b_out[n];
  float e = expf(logit);
  if (kh == 0) {
    stsc1(lggb + n, logit);             // raw logits for buddy out-softmax
    stsc1(smg + bb * NK + n, e);        // unnormalized e, stored EARLY
  }
  // S = sum_n e  (each n appears twice across lanes -> *0.5)
  float s = e;
  #pragma unroll
  for (int off = 32; off >= 1; off >>= 1) s += __shfl_xor(s, off);
  if ((tid & 63) == 0) wred[tid >> 6] = s;
  __syncthreads();
  float S = (wred[0] + wred[1] + wred[2] + wred[3]) * 0.5f;
  if (tid == 0) stsc1(sSb, S);          // persistent S (chunk boundary)
  asm volatile("s_waitcnt vmcnt(0)" ::: "memory");
  __syncthreads();
  if (fval && tid == 0) {
    ull v = ((ull)fval << 32) | (ull)__float_as_uint(S);
    stsc2u(smflag64, v);
  }
}

// ---------------- buddy: masked output softmax from global logits ----------
__device__ void c_head_out(int t, int bb, const float* __restrict__ mask,
                           float* __restrict__ out,
                           const float* __restrict__ lggb, float* wred) {
  const int tid = threadIdx.x;
  const int n = tid & 127;
  float lg = 0.0f;
  if (tid < 128)
    lg = __hip_atomic_load(lggb + n, __ATOMIC_RELAXED, __HIP_MEMORY_SCOPE_SYSTEM);
  float mk = (tid < 128) ? mask[bb * Tz + t] : 1.0f;
  float lm = (tid < 128) ? (lg + (1.0f - mk) * (-1e32f)) : -3.0e38f;
  float m2 = lm;
  #pragma unroll
  for (int off = 32; off >= 1; off >>= 1) m2 = fmaxf(m2, __shfl_xor(m2, off));
  if ((tid & 63) == 0 && tid < 128) wred[4 + (tid >> 6)] = m2;
  __syncthreads();
  float M2 = fmaxf(wred[4], wred[5]);
  float e2 = (tid < 128) ? expf(lm - M2) : 0.0f;
  float s2r = e2;
  #pragma unroll
  for (int off = 32; off >= 1; off >>= 1) s2r += __shfl_xor(s2r, off);
  if ((tid & 63) == 0 && tid < 128) wred[6 + (tid >> 6)] = s2r;
  __syncthreads();
  float S2 = wred[6] + wred[7];
  if (tid < 128) out[((size_t)bb * Tz + t) * NK + n] = e2 / S2;
}

// ---------------- Xpre GEMM (r1's verified kernel, generalized) -----------
// Xpre[n][(t-t0)*32+b] = sum_k hiddens[b][t][k]*W_ih0[n][k] + b_ih0[n]+b_hh0[n]
__global__ void __launch_bounds__(256)
xpre_kernel(const float* __restrict__ hiddens, const float* __restrict__ W_ih0,
            const float* __restrict__ b_ih0, const float* __restrict__ b_hh0,
            float* __restrict__ Xpre, int t0, int colTiles, int cstride) {
  __shared__ float Ws[16][64];
  __shared__ float Hs[16][64];
  const int tid = threadIdx.x;
  const int bx = blockIdx.x % colTiles;
  const int by = blockIdx.x / colTiles;
  const int n0 = by * 64, c0 = bx * 64;
  const int tx = tid & 15, ty = tid >> 4;
  const int ldn = tid >> 2;
  const int ldk = (tid & 3) * 4;

  const int bb = ldn & 31;
  const int tt = t0 + (c0 >> 5) + (ldn >> 5);
  const float* hsrc = hiddens + ((size_t)bb * Tz + tt) * Dz + ldk;
  const float* wsrc = W_ih0 + (size_t)(n0 + ldn) * IN0 + ldk;

  float acc[4][4] = {};
  vf4 wv = *(const vf4*)(wsrc);
  vf4 hv = *(const vf4*)(hsrc);
  for (int k0 = 0; k0 < Dz; k0 += 16) {
    __syncthreads();
    Ws[ldk + 0][ldn] = wv.x; Ws[ldk + 1][ldn] = wv.y;
    Ws[ldk + 2][ldn] = wv.z; Ws[ldk + 3][ldn] = wv.w;
    Hs[ldk + 0][ldn] = hv.x; Hs[ldk + 1][ldn] = hv.y;
    Hs[ldk + 2][ldn] = hv.z; Hs[ldk + 3][ldn] = hv.w;
    __syncthreads();
    if (k0 + 16 < Dz) {
      wv = *(const vf4*)(wsrc + k0 + 16);
      hv = *(const vf4*)(hsrc + k0 + 16);
    }
    #pragma unroll
    for (int k = 0; k < 16; ++k) {
      vf4 a4 = *(const vf4*)&Ws[k][ty * 4];
      vf4 b4 = *(const vf4*)&Hs[k][tx * 4];
      acc[0][0] += a4.x * b4.x; acc[0][1] += a4.x * b4.y; acc[0][2] += a4.x * b4.z; acc[0][3] += a4.x * b4.w;
      acc[1][0] += a4.y * b4.x; acc[1][1] += a4.y * b4.y; acc[1][2] += a4.y * b4.z; acc[1][3] += a4.y * b4.w;
      acc[2][0] += a4.z * b4.x; acc[2][1] += a4.z * b4.y; acc[2][2] += a4.z * b4.z; acc[2][3] += a4.z * b4.w;
      acc[3][0] += a4.w * b4.x; acc[3][1] += a4.w * b4.y; acc[3][2] += a4.w * b4.z; acc[3][3] += a4.w * b4.w;
    }
  }
  #pragma unroll
  for (int i = 0; i < 4; ++i) {
    int n = n0 + ty * 4 + i;
    float bi = b_ih0[n] + b_hh0[n];
    vf4 v; v.x = acc[i][0] + bi; v.y = acc[i][1] + bi;
    v.z = acc[i][2] + bi; v.w = acc[i][3] + bi;
    *(vf4*)(Xpre + (size_t)n * cstride + c0 + tx * 4) = v;
  }
}

// ---------------- the persistent kernel -----------------------------------
__global__ void __launch_bounds__(256)
seq_kernel(const float* __restrict__ hiddens,
           const float* __restrict__ h_t, const float* __restrict__ c_t,
           const float* __restrict__ mask,
           const float* __restrict__ W_out, const float* __restrict__ b_out,
           const float* __restrict__ W_ih0, const float* __restrict__ W_hh0,
           const float* __restrict__ W_ih1, const float* __restrict__ W_hh1,
           const float* __restrict__ b_ih1, const float* __restrict__ b_hh1,
           const float* __restrict__ Xpre, float* __restrict__ out,
           float* __restrict__ h1g, float* __restrict__ h2g,
           float* __restrict__ smg, float* __restrict__ c1g, float* __restrict__ c2g,
           float* __restrict__ lgg, float* __restrict__ sSg,
           unsigned int* bar, int t0, int nsteps, int cstride) {
  __shared__ float wA[16][640];     // [W_hh0(512) | W_ih0 sm-cols(128)]
  __shared__ float wB[16][1024];    // [W_ih1(512) | W_hh1(512)]
  __shared__ float gbuf[16][17];
  __shared__ float biasB[16];
  __shared__ float hsg[512];
  __shared__ float wred[8];
  __shared__ float sSl[16];         // per-batch 1/S for this pg group

  const int tid = threadIdx.x;
  const int bid = blockIdx.x;
  const int jg  = bid >> 1;          // j-group 0..127 (4 hidden units)
  const int pg  = bid & 1;           // batch-group 0..1 (16 batches)
  const int ks  = tid & 15;          // k-slice 0..15
  const int bbl = tid >> 4;          // local batch 0..15
  const int bbg = pg * 16 + bbl;     // global batch
  const int ks4 = ks * 4;
  const int cu  = tid & 3, cbl = tid >> 2;   // GATES mapping (tid<64)
  const int rr  = ((ks & 1) << 3) | ((ks & 2) << 1) | ((ks & 4) >> 1) | ((ks & 8) >> 3);
  const int rowG = ((rr >> 2) * Hz) + jg * 4 + (rr & 3);   // butterfly-out row
  // head blocks: bid<32; batch remapped into the block's own pg-group.
  const int hb = ((bid & 1) << 4) | (bid >> 1);
  // buddy blocks: bid in [32,64); masked out-softmax for batch bb2 (own pg).
  const bool isbud = (bid >= 32 && bid < 64);
  const int  bb2   = isbud ? (((bid & 1) << 4) | ((bid >> 1) - 16)) : 0;

  // bar layout (uints): [0..2047] g0 slots (64B stride), [2048..4095] g1
  // slots, [4096 + pg*16] bcast words, [4608 + b*16] sm flag64s (8B-aligned).
  unsigned int* barg = bar + pg * 2048;
  unsigned int* bcst = bar + 4096 + pg * 16;
  unsigned int* smf  = bar + 4608;
  const int  gidx    = bid >> 1;            // slot index within group
  const bool gmaster = (gidx == 127);       // bid 254 / 255

  // ---- one-time: weights -> LDS (block-private rows, read-only source) ----
  #pragma clang loop unroll(disable)
  for (int r = 0; r < 16; ++r) {
    const int row = ((r >> 2) * Hz) + jg * 4 + (r & 3);
    if (tid * 4 < 512)
      *(vf4*)&wA[r][tid * 4] = *(const vf4*)(W_hh0 + (size_t)row * Hz + tid * 4);
    if (tid * 4 < 128)
      *(vf4*)&wA[r][512 + tid * 4] = *(const vf4*)(W_ih0 + (size_t)row * IN0 + 1024 + tid * 4);
    if (tid * 4 < 512) {
      *(vf4*)&wB[r][tid * 4]       = *(const vf4*)(W_ih1 + (size_t)row * Hz + tid * 4);
      *(vf4*)&wB[r][512 + tid * 4] = *(const vf4*)(W_hh1 + (size_t)row * Hz + tid * 4);
    }
  }
  if (tid < 16) {
    const int row = ((tid >> 2) * Hz) + jg * 4 + (tid & 3);
    biasB[tid] = b_ih1[row] + b_hh1[row];
  }

  // ---- c-state in registers (tid<64: unit cu, batch cbl) ----
  float c1r = 0.0f, c2r = 0.0f;
  if (tid < 64) {
    const size_t ci = (size_t)(pg * 16 + cbl) * Hz + jg * 4 + cu;
    if (t0 == 0) { c1r = c_t[ci]; c2r = c_t[BH + ci]; }
    else         { c1r = c1g[ci]; c2r = c2g[ci]; }
  }

  if (t0 == 0) {
    // stage h_t into parity-1 h buffers; compute e/S(-1)
    if (bid < 32 && tid < 128) {
      vf4 v1 = *(const vf4*)(h_t + (size_t)hb * Hz + tid * 4);
      vf4 v2 = *(const vf4*)(h_t + BH + (size_t)hb * Hz + tid * 4);
      float* d1 = h1g + BH + (size_t)hb * Hz + tid * 4;
      float* d2 = h2g + BH + (size_t)hb * Hz + tid * 4;
      stsc1(d1, v1.x); stsc1(d1 + 1, v1.y); stsc1(d1 + 2, v1.z); stsc1(d1 + 3, v1.w);
      stsc1(d2, v2.x); stsc1(d2 + 1, v2.y); stsc1(d2 + 2, v2.z); stsc1(d2 + 3, v2.w);
    }
    if (bid < 32) {
      if (tid < 128)
        *(vf4*)&hsg[tid * 4] = *(const vf4*)(hiddens + (size_t)hb * Tz * Dz + tid * 4);
      __syncthreads();
      c_head_crit(hsg, hb, W_out, b_out, smg, lgg + hb * NK, sSg + hb, wred,
                  (ull*)(smf + hb * 16), 0u);
    }
  }
  __syncthreads();
  unsigned int g = 1;
  gbar(barg, bcst, gidx, gmaster, g); ++g;      // g is now 2

  // ---- loop-carried phase-A operands: ca = h1prev(t) [= prev iter's aa] --
  vf4 ca0,ca1,ca2,ca3,ca4,ca5,ca6,ca7;
  {
    const float* hp = h1g + ((t0 + 1) & 1) * BH + (size_t)bbg * Hz + ks4;
    ldsc4(ca0, hp);        ldsc4(ca1, hp + 64);  ldsc4(ca2, hp + 128);
    ldsc4(ca3, hp + 192);  ldsc4(ca4, hp + 256); ldsc4(ca5, hp + 320);
    ldsc4(ca6, hp + 384);  ldsc4(ca7, hp + 448);
    FENCE8(0, ca0,ca1,ca2,ca3,ca4,ca5,ca6,ca7);
  }

  #pragma clang loop unroll(disable)
  for (int k = 0; k < nsteps; ++k) {
    const int t = t0 + k;
    float*       h1cur  = h1g + (t & 1) * BH;
    const float* h2prev = h2g + ((t + 1) & 1) * BH;
    float*       h2cur  = h2g + (t & 1) * BH;
    float A0,A1,A2,A3,A4,A5,A6,A7,A8,A9,A10,A11,A12,A13,A14,A15;
    vf4 ab0,ab1,ab2,ab3,ab4,ab5,ab6,ab7;   // phase-B h2prev operands

    // ============ Phase A: layer-0 gates (ah = carried ca regs) ===========
    {
      vf4 as0,as1;
      float xv;
      ldg1(xv, Xpre + (size_t)rowG * cstride + k * 32 + bbg);
      ZERO16
      R16A(FMAROW, ca0, wA, ks4 +   0)
      R16A(FMAROW, ca1, wA, ks4 +  64)
      R16A(FMAROW, ca2, wA, ks4 + 128)
      R16A(FMAROW, ca3, wA, ks4 + 192)
      R16A(FMAROW, ca4, wA, ks4 + 256)
      R16A(FMAROW, ca5, wA, ks4 + 320)
      R16A(FMAROW, ca6, wA, ks4 + 384)
      R16A(FMAROW, ca7, wA, ks4 + 448)
      RED16
      const float partA = A0;            // ah contribution, reduced (1 reg)
      // ---- acquire e/S(t-1): tid<16 poll flag64 {cnt,S} (tiny live set) --
      if (k > 0) {
        const unsigned int tgt = (unsigned int)k;
        if (tid < 16) {
          const ull* fp = (const ull*)(smf + (pg * 16 + tid) * 16);
          ull v;
          for (;;) {
            v = __hip_atomic_load(fp, __ATOMIC_RELAXED, __HIP_MEMORY_SCOPE_SYSTEM);
            if ((unsigned int)(v >> 32) >= tgt) break;
            __builtin_amdgcn_s_sleep(1);
          }
          sSl[tid] = 1.0f / __uint_as_float((unsigned int)v);
        }
        __syncthreads();
        // buddy: masked out-softmax for step t-1 (fills flag-wait slack;
        // logits(t-1) were drained before flag k was released).
        if (isbud)
          c_head_out(t - 1, bb2, mask, out, lgg + bb2 * NK, wred);
      } else {
        if (tid < 16) sSl[tid] = 1.0f / ldsc1f(sSg + pg * 16 + tid);
        __syncthreads();
      }
      const float* sp = smg + (size_t)bbg * NK + ks4;
      ldsc4(as0, sp);        ldsc4(as1, sp + 64);
      ZERO16
      asm volatile("s_waitcnt vmcnt(0)" : "+v"(as0), "+v"(as1), "+v"(xv) :: "memory");
      R16A(FMAROW, as0, wA, ks4 + 512)
      R16A(FMAROW, as1, wA, ks4 + 576)
      RED16
      // A0 = Sum W*e for (row rr, batch bbl); scale by 1/S at the end.
      gbuf[rr][bbl] = partA + A0 * sSl[bbl] + xv;  // Xpre includes biases
      GATES(c1r, h1cur)
    }
    // ---- prefetch phase-B ab (h2prev) BEFORE P1 arrive: the garrive drain
    // (vmcnt(0)) covers the h1 store AND these loads in one latency window.
    // (h2prev(t-1) visibility via the flag chain; garrive has no poll.)
    {
      const float* p2 = h2prev + (size_t)bbg * Hz + ks4;
      ldsc4(ab0, p2);       ldsc4(ab1, p2 + 64);  ldsc4(ab2, p2 + 128);
      ldsc4(ab3, p2 + 192); ldsc4(ab4, p2 + 256); ldsc4(ab5, p2 + 320);
      ldsc4(ab6, p2 + 384); ldsc4(ab7, p2 + 448);
    }
    const unsigned int gA = g;
    garrive(barg, gidx, gA); ++g;               // P1 arrive (h1cur published)

    // ============ Phase B: ab-half first, deferred P1 wait at boundary ====
    {
      ZERO16
      // ab data landed (garrive drained vmcnt(0)); compile-order tie only.
      FENCE8(0, ab0,ab1,ab2,ab3,ab4,ab5,ab6,ab7);
      R16A(FMAROW, ab0, wB, ks4 + 512)
      R16A(FMAROW, ab1, wB, ks4 + 576)
      R16A(FMAROW, ab2, wB, ks4 + 640)
      R16A(FMAROW, ab3, wB, ks4 + 704)
      R16A(FMAROW, ab4, wB, ks4 + 768)
      R16A(FMAROW, ab5, wB, ks4 + 832)
      R16A(FMAROW, ab6, wB, ks4 + 896)
      R16A(FMAROW, ab7, wB, ks4 + 960)
      RED16
      const float partB = A0;            // W_hh1*h2prev, reduced (1 reg)
      // ---- deferred P1 wait: single-level all-poll (1 RT, no bcast) ------
      if (tid < 128) {
        unsigned int* wsl = barg + tid * 16;
        while (__hip_atomic_load(wsl, __ATOMIC_RELAXED,
                                 __HIP_MEMORY_SCOPE_SYSTEM) < gA)
          __builtin_amdgcn_s_sleep(1);
      }
      __syncthreads();
      // ---- aa half (h1cur, now synced) -> loads into CARRIED ca regs -----
      const float* p1 = h1cur + (size_t)bbg * Hz + ks4;
      ldsc4(ca0, p1);       ldsc4(ca1, p1 + 64);  ldsc4(ca2, p1 + 128);
      ldsc4(ca3, p1 + 192); ldsc4(ca4, p1 + 256); ldsc4(ca5, p1 + 320);
      ldsc4(ca6, p1 + 384); ldsc4(ca7, p1 + 448);
      ZERO16
      FENCE8(0, ca0,ca1,ca2,ca3,ca4,ca5,ca6,ca7);
      R16A(FMAROW, ca0, wB, ks4 +   0)
      R16A(FMAROW, ca1, wB, ks4 +  64)
      R16A(FMAROW, ca2, wB, ks4 + 128)
      R16A(FMAROW, ca3, wB, ks4 + 192)
      R16A(FMAROW, ca4, wB, ks4 + 256)
      R16A(FMAROW, ca5, wB, ks4 + 320)
      R16A(FMAROW, ca6, wB, ks4 + 384)
      R16A(FMAROW, ca7, wB, ks4 + 448)
      RED16
      gbuf[rr][bbl] = A0 + partB + biasB[rr];
      GATES(c2r, h2cur)
    }
    const unsigned int gB = g;
    garrive(barg, gidx, gB); ++g;               // P2 arrive; workers sail on

    // ============ head bottom: sm-critical for step t (ca stays live) =====
    if (bid < 32) {
      // wait all group blocks arrived P2 (h2cur complete)
      if (tid < 128) {
        unsigned int* wsl = barg + tid * 16;
        while (__hip_atomic_load(wsl, __ATOMIC_RELAXED,
                                 __HIP_MEMORY_SCOPE_SYSTEM) < gB)
          __builtin_amdgcn_s_sleep(1);
      }
      __syncthreads();
      if (tid < 128) {
        vf4 v;
        ldsc4(v, h2cur + (size_t)hb * Hz + tid * 4);
        asm volatile("s_waitcnt vmcnt(0)" : "+v"(v) :: "memory");
        *(vf4*)&hsg[tid * 4] = v;
      }
      __syncthreads();
      c_head_crit(hsg, hb, W_out, b_out, smg, lgg + hb * NK, sSg + hb, wred,
                  (ull*)(smf + hb * 16), (unsigned int)(k + 1));
    }
  }

  // ===== epilogue: buddies emit out(t_last) after final flag ==============
  if (isbud) {
    if (tid == 0) {
      const ull* fp = (const ull*)(smf + bb2 * 16);
      while ((unsigned int)(__hip_atomic_load(fp, __ATOMIC_RELAXED,
                              __HIP_MEMORY_SCOPE_SYSTEM) >> 32) < (unsigned int)nsteps)
        __builtin_amdgcn_s_sleep(1);
    }
    __syncthreads();
    c_head_out(t0 + nsteps - 1, bb2, mask, out, lgg + bb2 * NK, wred);
  }

  // spill c-state for next chunk (no-op cost in full path)
  if (tid < 64) {
    const size_t ci = (size_t)(pg * 16 + cbl) * Hz + jg * 4 + cu;
    stsc1(c1g + ci, c1r);
    stsc1(c2g + ci, c2r);
  }
}

// ---------------------------------------------------------------------------
extern "C" void kernel_launch(void* const* d_in, const int* in_sizes, int n_in,
                              void* d_out, int out_size, void* d_ws, size_t ws_size,
                              hipStream_t stream) {
  (void)in_sizes; (void)n_in; (void)out_size;
  const float* hiddens = (const float*)d_in[0];
  const float* h_t     = (const float*)d_in[1];
  const float* c_t     = (const float*)d_in[2];
  const float* mask    = (const float*)d_in[3];
  const float* W_out   = (const float*)d_in[4];
  const float* b_out   = (const float*)d_in[5];
  const float* W_ih0   = (const float*)d_in[6];
  const float* W_hh0   = (const float*)d_in[7];
  const float* b_ih0   = (const float*)d_in[8];
  const float* b_hh0   = (const float*)d_in[9];
  const float* W_ih1   = (const float*)d_in[10];
  const float* W_hh1   = (const float*)d_in[11];
  const float* b_ih1   = (const float*)d_in[12];
  const float* b_hh1   = (const float*)d_in[13];
  float* out = (float*)d_out;

  unsigned int* bar = (unsigned int*)d_ws;                 // 32 KB
  float* base = (float*)((char*)d_ws + 32768);
  float* h1g  = base;                                      // 2*BH
  float* h2g  = h1g + 2 * BH;                              // 2*BH
  float* smg  = h2g + 2 * BH;                              // Bz*NK (e values)
  float* c1g  = smg + Bz * NK;                             // BH
  float* c2g  = c1g + BH;                                  // BH
  float* lgg  = c2g + BH;                                  // Bz*NK raw logits
  float* sSg  = lgg + Bz * NK;                             // Bz persistent S
  float* Xpre = sSg + 64;                                  // full: 2048*8192

  const size_t fullNeed = 32768 + (size_t)(102400 + Bz * NK + 64 + 2048 * 8192) * 4;
  const bool full = ws_size >= fullNeed;
  const int NCH    = full ? 1 : 16;
  const int CH     = full ? Tz : 16;
  const int cstr   = full ? (Tz * 32) : (16 * 32);
  const int cTiles = cstr / 64;

  for (int c = 0; c < NCH; ++c) {
    const int t0 = c * CH;
    hipMemsetAsync(bar, 0, 32768, stream);
    hipLaunchKernelGGL(xpre_kernel, dim3(32 * cTiles), dim3(256), 0, stream,
                       hiddens, W_ih0, b_ih0, b_hh0, Xpre, t0, cTiles, cstr);
    int nsteps = CH, cs = cstr, tt0 = t0;
    void* ka[] = { (void*)&hiddens, (void*)&h_t, (void*)&c_t, (void*)&mask,
                   (void*)&W_out, (void*)&b_out, (void*)&W_ih0, (void*)&W_hh0,
                   (void*)&W_ih1, (void*)&W_hh1, (void*)&b_ih1, (void*)&b_hh1,
                   (void*)&Xpre, (void*)&out, (void*)&h1g, (void*)&h2g,
                   (void*)&smg, (void*)&c1g, (void*)&c2g, (void*)&lgg,
                   (void*)&sSg, (void*)&bar, (void*)&tt0, (void*)&nsteps,
                   (void*)&cs };
    hipError_t err = hipLaunchCooperativeKernel((void*)seq_kernel, dim3(NBLK),
                                                dim3(256), ka, 0, stream);
    if (err != hipSuccess) {
      // fallback: plain launch; 256 blocks at 1 block/CU are co-resident.
      hipLaunchKernelGGL(seq_kernel, dim3(NBLK), dim3(256), 0, stream,
                         hiddens, h_t, c_t, mask, W_out, b_out, W_ih0, W_hh0,
                         W_ih1, W_hh1, b_ih1, b_hh1, Xpre, out,
                         h1g, h2g, smg, c1g, c2g, lgg, sSg, bar, tt0, nsteps, cs);
    }
  }
}